// Round 1
// baseline (2606.100 us; speedup 1.0000x reference)
//
#include <hip/hip_runtime.h>

// AGLI_5703716569604 — full f32 implementation, round 0 (correctness-first).
// Shapes: B=2, ch1=64, ch2=128, H=W=64, N=4096 (spatial), att is [B,4096,4096].

#define LB __launch_bounds__(256)

constexpr float BN_SCALE = 0.99999500003749968f; // 1/sqrt(1+1e-5)
constexpr float NEG_BIG  = -3.402823466e38f;

// ---------------------------------------------------------------------------
// Generic direct 3x3 conv (pad=1) + optional const-broadcast channels +
// optional bias + BN(gamma,beta eval-mode) + ReLU + optional residual.
// grid: (H*W/256, Cout, B), block 256
__global__ LB void conv3x3_bcr(
    const float* __restrict__ in,       // [B, Cin, H, W]
    const float* __restrict__ gconst,   // [B, Cg] or nullptr
    const float* __restrict__ w,        // [Cout, Cg+Cin, 3, 3]
    const float* __restrict__ bias,     // [Cout] or nullptr
    const float* __restrict__ bn,       // [2, Cout]
    const float* __restrict__ residual, // [B, Cout, H, W] or nullptr
    float* __restrict__ out,
    int B, int Cg, int Cin, int Cout, int H, int W)
{
    const int tid = threadIdx.x;
    const long HW = (long)H * W;
    const long hw = (long)blockIdx.x * 256 + tid;
    if (hw >= HW) return;
    const int oc = blockIdx.y;
    const int b  = blockIdx.z;
    const int x = (int)(hw % W);
    const int y = (int)(hw / W);
    const int Ct = Cg + Cin;
    const float* wp = w + (long)oc * Ct * 9;

    float acc = bias ? bias[oc] : 0.0f;

    for (int ic = 0; ic < Cg; ++ic) {
        const float gv = gconst[b * Cg + ic];
        const float* wq = wp + ic * 9;
        float wsum = 0.f;
        #pragma unroll
        for (int dy = 0; dy < 3; ++dy) {
            const int yy = y + dy - 1;
            if (yy < 0 || yy >= H) continue;
            #pragma unroll
            for (int dx = 0; dx < 3; ++dx) {
                const int xx = x + dx - 1;
                if (xx < 0 || xx >= W) continue;
                wsum += wq[dy * 3 + dx];
            }
        }
        acc += wsum * gv;
    }
    for (int ic = 0; ic < Cin; ++ic) {
        const float* ip = in + ((long)(b * Cin + ic)) * HW;
        const float* wq = wp + (Cg + ic) * 9;
        #pragma unroll
        for (int dy = 0; dy < 3; ++dy) {
            const int yy = y + dy - 1;
            if (yy < 0 || yy >= H) continue;
            #pragma unroll
            for (int dx = 0; dx < 3; ++dx) {
                const int xx = x + dx - 1;
                if (xx < 0 || xx >= W) continue;
                acc = fmaf(wq[dy * 3 + dx], ip[(long)yy * W + xx], acc);
            }
        }
    }
    const float scale = bn[oc] * BN_SCALE;
    const float beta  = bn[Cout + oc];
    float v = fmaxf(fmaf(acc, scale, beta), 0.0f);
    const long oidx = ((long)(b * Cout + oc)) * HW + hw;
    if (residual) v += residual[oidx];
    out[oidx] = v;
}

// ---------------------------------------------------------------------------
// Global average pool of [B,C,HW] -> writes mean to two destinations [B,C].
// grid: (C, B), block 256
__global__ LB void gap_kernel(const float* __restrict__ in,
                              float* __restrict__ o1, float* __restrict__ o2,
                              int C, int HW)
{
    const int c = blockIdx.x, b = blockIdx.y;
    const float* p = in + ((long)b * C + c) * HW;
    float s = 0.f;
    for (int i = threadIdx.x; i < HW; i += 256) s += p[i];
    #pragma unroll
    for (int off = 32; off; off >>= 1) s += __shfl_down(s, off);
    __shared__ float red[4];
    if ((threadIdx.x & 63) == 0) red[threadIdx.x >> 6] = s;
    __syncthreads();
    if (threadIdx.x == 0) {
        const float t = (red[0] + red[1] + red[2] + red[3]) / (float)HW;
        o1[b * C + c] = t;
        o2[b * C + c] = t;
    }
}

// ---------------------------------------------------------------------------
// att[b,n,m] = sum_c fs[b,c,n] * fc[b,c,m], C=32.
// grid: (N/256, N/16, B), block 256 (one m per thread, 16 n-rows per block)
__global__ LB void att_gemm(const float* __restrict__ fs, const float* __restrict__ fc,
                            float* __restrict__ att, int N)
{
    __shared__ float lfs[32][17];
    const int tid = threadIdx.x;
    const int m  = blockIdx.x * 256 + tid;
    const int n0 = blockIdx.y * 16;
    const int b  = blockIdx.z;
    for (int i = tid; i < 32 * 16; i += 256) {
        const int c = i >> 4, nn = i & 15;
        lfs[c][nn] = fs[((long)b * 32 + c) * N + n0 + nn];
    }
    __syncthreads();
    float acc[16];
    #pragma unroll
    for (int i = 0; i < 16; ++i) acc[i] = 0.f;
    const float* fcp = fc + (long)b * 32 * N + m;
    #pragma unroll
    for (int c = 0; c < 32; ++c) {
        const float f = fcp[(long)c * N];
        #pragma unroll
        for (int nn = 0; nn < 16; ++nn) acc[nn] = fmaf(lfs[c][nn], f, acc[nn]);
    }
    float* op = att + ((long)b * N + n0) * N + m;
    #pragma unroll
    for (int nn = 0; nn < 16; ++nn) op[(long)nn * N] = acc[nn];
}

// ---------------------------------------------------------------------------
// Column-wise online (max, sum-exp) over an n-chunk. grid: (N/256, S, B)
__global__ LB void colstats_part(const float* __restrict__ att,
                                 float* __restrict__ Mp, float* __restrict__ Sp,
                                 int N, int S)
{
    const int m = blockIdx.x * 256 + threadIdx.x;
    const int s = blockIdx.y, b = blockIdx.z;
    const int chunk = N / S;
    const float* p = att + (long)b * N * N + (long)s * chunk * N + m;
    float mx = NEG_BIG, sum = 0.f;
    for (int n = 0; n < chunk; ++n) {
        const float v = p[(long)n * N];
        if (v > mx) { sum = sum * __expf(mx - v) + 1.f; mx = v; }
        else        { sum += __expf(v - mx); }
    }
    Mp[((long)b * S + s) * N + m] = mx;
    Sp[((long)b * S + s) * N + m] = sum;
}

// grid: (N/256, B)
__global__ LB void colstats_comb(const float* __restrict__ Mp, const float* __restrict__ Sp,
                                 float* __restrict__ M, float* __restrict__ Sm,
                                 int N, int S)
{
    const int m = blockIdx.x * 256 + threadIdx.x;
    const int b = blockIdx.y;
    float mx = NEG_BIG, sum = 0.f;
    for (int s = 0; s < S; ++s) {
        const float m2 = Mp[((long)b * S + s) * N + m];
        const float s2 = Sp[((long)b * S + s) * N + m];
        const float mn = fmaxf(mx, m2);
        sum = sum * __expf(mx - mn) + s2 * __expf(m2 - mn);
        mx = mn;
    }
    M[(long)b * N + m]  = mx;
    Sm[(long)b * N + m] = sum;
}

// ---------------------------------------------------------------------------
// Row-wise (max, sum-exp). grid: (N, B), block 256
__global__ LB void rowstats(const float* __restrict__ att,
                            float* __restrict__ Mr, float* __restrict__ Sr, int N)
{
    const int n = blockIdx.x, b = blockIdx.y;
    const float* p = att + ((long)b * N + n) * N;
    float mx = NEG_BIG, sum = 0.f;
    for (int m = threadIdx.x; m < N; m += 256) {
        const float v = p[m];
        if (v > mx) { sum = sum * __expf(mx - v) + 1.f; mx = v; }
        else        { sum += __expf(v - mx); }
    }
    #pragma unroll
    for (int off = 32; off; off >>= 1) {
        const float m2 = __shfl_down(mx, off);
        const float s2 = __shfl_down(sum, off);
        const float mn = fmaxf(mx, m2);
        sum = sum * __expf(mx - mn) + s2 * __expf(m2 - mn);
        mx = mn;
    }
    __shared__ float rm[4], rs[4];
    const int lane = threadIdx.x & 63, wv = threadIdx.x >> 6;
    if (lane == 0) { rm[wv] = mx; rs[wv] = sum; }
    __syncthreads();
    if (threadIdx.x == 0) {
        mx = rm[0]; sum = rs[0];
        for (int w = 1; w < 4; ++w) {
            const float mn = fmaxf(mx, rm[w]);
            sum = sum * __expf(mx - mn) + rs[w] * __expf(rm[w] - mn);
            mx = mn;
        }
        Mr[(long)b * N + n] = mx;
        Sr[(long)b * N + n] = sum;
    }
}

// ---------------------------------------------------------------------------
// outs partial: part[b,s,c,m] = sum_{n in chunk s} xs1[b,c,n]*exp(att[n,m]-Mc[m])
// grid: (N/256, S, B); C=64 fixed.
__global__ LB void outs_part(const float* __restrict__ att, const float* __restrict__ xs1,
                             const float* __restrict__ Mc, float* __restrict__ part,
                             int N, int S)
{
    __shared__ float lxt[64][68]; // [nn][c], padded for b128-aligned rows
    const int tid = threadIdx.x;
    const int m = blockIdx.x * 256 + tid;
    const int s = blockIdx.y, b = blockIdx.z;
    const int chunk = N / S;
    float acc[64];
    #pragma unroll
    for (int c = 0; c < 64; ++c) acc[c] = 0.f;
    const float mcv = Mc[(long)b * N + m];
    const float* attb = att + (long)b * N * N + m;
    const float* xb = xs1 + (long)b * 64 * N;
    for (int n0 = s * chunk; n0 < (s + 1) * chunk; n0 += 64) {
        __syncthreads();
        #pragma unroll
        for (int i = 0; i < 16; ++i) {
            const int e = tid + i * 256;
            const int c = e >> 6, nn = e & 63;
            lxt[nn][c] = xb[(long)c * N + n0 + nn];
        }
        __syncthreads();
        for (int nn = 0; nn < 64; ++nn) {
            const float ev = __expf(attb[(long)(n0 + nn) * N] - mcv);
            #pragma unroll
            for (int c4 = 0; c4 < 16; ++c4) {
                const float4 xv = *(const float4*)&lxt[nn][c4 * 4];
                acc[c4 * 4 + 0] = fmaf(xv.x, ev, acc[c4 * 4 + 0]);
                acc[c4 * 4 + 1] = fmaf(xv.y, ev, acc[c4 * 4 + 1]);
                acc[c4 * 4 + 2] = fmaf(xv.z, ev, acc[c4 * 4 + 2]);
                acc[c4 * 4 + 3] = fmaf(xv.w, ev, acc[c4 * 4 + 3]);
            }
        }
    }
    float* pp = part + ((long)(b * S + s) * 64) * N + m;
    #pragma unroll
    for (int c = 0; c < 64; ++c) pp[(long)c * N] = acc[c];
}

// grid: (B*64*N/256). N==4096 assumed (shifts).
__global__ LB void outs_reduce(const float* __restrict__ part, const float* __restrict__ Sc,
                               float* __restrict__ outs, int N, int S)
{
    const long idx = (long)blockIdx.x * 256 + threadIdx.x;
    const int m = (int)(idx & (long)(N - 1));
    const long bc = idx >> 12;
    const int c = (int)(bc & 63);
    const int b = (int)(bc >> 6);
    float s = 0.f;
    for (int ss = 0; ss < S; ++ss)
        s += part[((long)(b * S + ss) * 64 + c) * N + m];
    outs[idx] = s / Sc[(long)b * N + m];
}

// ---------------------------------------------------------------------------
// Materialize row-softmax: smr[b,n,m] = exp(att - Mr[n]) / Sr[n].
// grid: (16*N, B); 16 blocks per row, block 256.
__global__ LB void smr_mat(const float* __restrict__ att, const float* __restrict__ Mr,
                           const float* __restrict__ Sr, float* __restrict__ smr, int N)
{
    const int b = blockIdx.y;
    const int n = blockIdx.x >> 4;
    const int m = ((blockIdx.x & 15) << 8) + threadIdx.x;
    const long idx = ((long)b * N + n) * N + m;
    smr[idx] = __expf(att[idx] - Mr[(long)b * N + n]) / Sr[(long)b * N + n];
}

// ---------------------------------------------------------------------------
// outc[b,c,j] = sum_m xc1[b,c,m] * smr[b,j,m]   (C = A·B^T), Cch=128.
// grid: (N/64, 2, B), block 256; 64x64 tile, 4x4 per thread, m-chunk 32.
__global__ LB void outc_gemm(const float* __restrict__ A, const float* __restrict__ Bm,
                             float* __restrict__ C, int N)
{
    __shared__ float aT[32][68]; // [mm][c]
    __shared__ float bT[32][68]; // [mm][j]
    const int tid = threadIdx.x;
    const int j0 = blockIdx.x * 64, c0 = blockIdx.y * 64, b = blockIdx.z;
    const int tx = tid & 15, ty = tid >> 4;
    float acc[4][4];
    #pragma unroll
    for (int i = 0; i < 4; ++i)
        #pragma unroll
        for (int k = 0; k < 4; ++k) acc[i][k] = 0.f;
    const float* Ab = A + ((long)b * 128 + c0) * N;
    const float* Bb = Bm + ((long)b * N + j0) * N;
    for (int m0 = 0; m0 < N; m0 += 32) {
        __syncthreads();
        #pragma unroll
        for (int i = 0; i < 8; ++i) {
            const int e = tid + i * 256;
            const int row = e >> 5, col = e & 31;
            aT[col][row] = Ab[(long)row * N + m0 + col];
            bT[col][row] = Bb[(long)row * N + m0 + col];
        }
        __syncthreads();
        #pragma unroll
        for (int mm = 0; mm < 32; ++mm) {
            const float4 av = *(const float4*)&aT[mm][ty << 2];
            const float4 bv = *(const float4*)&bT[mm][tx << 2];
            const float a[4] = {av.x, av.y, av.z, av.w};
            const float bb[4] = {bv.x, bv.y, bv.z, bv.w};
            #pragma unroll
            for (int i = 0; i < 4; ++i)
                #pragma unroll
                for (int k = 0; k < 4; ++k)
                    acc[i][k] = fmaf(a[i], bb[k], acc[i][k]);
        }
    }
    #pragma unroll
    for (int i = 0; i < 4; ++i) {
        float* cp = C + ((long)b * 128 + c0 + (ty << 2) + i) * N + j0 + (tx << 2);
        *(float4*)cp = make_float4(acc[i][0], acc[i][1], acc[i][2], acc[i][3]);
    }
}

// ---------------------------------------------------------------------------
// In-place att += att^T via 32x32 tile pairs. grid: (N/32, N/32, B); ti<=tj work.
__global__ LB void att2_sym(float* __restrict__ att, int N)
{
    const int ti = blockIdx.x, tj = blockIdx.y;
    if (ti > tj) return;
    const int b = blockIdx.z;
    __shared__ float Ta[32][33], Tb[32][33];
    const long base = (long)b * N * N;
    const int tid = threadIdx.x;
    const int r = tid >> 5, col = tid & 31;
    #pragma unroll
    for (int i = 0; i < 4; ++i) {
        const int rr = r + i * 8;
        Ta[rr][col] = att[base + (long)(ti * 32 + rr) * N + tj * 32 + col];
        Tb[rr][col] = att[base + (long)(tj * 32 + rr) * N + ti * 32 + col];
    }
    __syncthreads();
    #pragma unroll
    for (int i = 0; i < 4; ++i) {
        const int rr = r + i * 8;
        att[base + (long)(ti * 32 + rr) * N + tj * 32 + col] = Ta[rr][col] + Tb[col][rr];
        if (ti != tj)
            att[base + (long)(tj * 32 + rr) * N + ti * 32 + col] = Tb[rr][col] + Ta[col][rr];
    }
}

// ---------------------------------------------------------------------------
// In-place att3 = 2*exp(att2 - M2[m]) / S2[m]. grid: (16*N, B).
__global__ LB void att3_mat(float* __restrict__ att, const float* __restrict__ M2,
                            const float* __restrict__ S2, int N)
{
    const int b = blockIdx.y;
    const int n = blockIdx.x >> 4;
    const int m = ((blockIdx.x & 15) << 8) + threadIdx.x;
    const long idx = ((long)b * N + n) * N + m;
    att[idx] = 2.f * __expf(att[idx] - M2[(long)b * N + m]) / S2[(long)b * N + m];
}

// ===========================================================================
extern "C" void kernel_launch(void* const* d_in, const int* in_sizes, int n_in,
                              void* d_out, int out_size, void* d_ws, size_t ws_size,
                              hipStream_t stream)
{
    const float* xs   = (const float*)d_in[0];
    const float* xc   = (const float*)d_in[1];
    const float* w_g1 = (const float*)d_in[2];
    const float* g_g1 = (const float*)d_in[3];
    const float* w_g2 = (const float*)d_in[4];
    const float* g_g2 = (const float*)d_in[5];
    const float* w_ls = (const float*)d_in[6];
    const float* b_ls = (const float*)d_in[7];
    const float* g_ls = (const float*)d_in[8];
    const float* w_lc = (const float*)d_in[9];
    const float* b_lc = (const float*)d_in[10];
    const float* g_lc = (const float*)d_in[11];
    const float* w_c1 = (const float*)d_in[12];
    const float* g_c1 = (const float*)d_in[13];
    const float* w_c2 = (const float*)d_in[14];
    const float* g_c2 = (const float*)d_in[15];
    const float* w_o1 = (const float*)d_in[16];
    const float* g_o1 = (const float*)d_in[17];
    const float* w_o2 = (const float*)d_in[18];
    const float* g_o2 = (const float*)d_in[19];
    const float* w_oa = (const float*)d_in[20];
    const float* g_oa = (const float*)d_in[21];

    const int B = 2, H = 64, W = 64, HW = 4096, N = 4096;

    // ---- workspace layout (float offsets) ----
    float* ws = (float*)d_ws;
    float* xs1    = ws;                       // 524288
    float* xc1    = ws + 524288;              // 1048576
    float* fs     = ws + 1572864;             // 262144
    float* fc     = ws + 1835008;             // 262144
    float* t32    = ws + 2097152;             // 262144
    float* outs_w = ws + 2359296;             // 524288
    float* outc_w = ws + 2883584;             // 1048576
    float* gs_w   = ws + 3932160;             // 64
    float* gc_w   = ws + 3932224;             // 64
    float* Mc     = ws + 3932288;             // 8192
    float* Sc     = ws + 3940480;             // 8192
    float* Mr     = ws + 3948672;             // 8192
    float* Sr     = ws + 3956864;             // 8192
    float* M2     = ws + 3965056;             // 8192
    float* S2     = ws + 3973248;             // 8192
    float* Mp     = ws + 3981440;             // 131072 (B*16*N)
    float* Sp     = ws + 4112512;             // 131072
    float* att    = ws + 4243584;             // 33554432  (-> 37798016 floats total)

    // ---- d_out layout ----
    float* out = (float*)d_out;
    float* out_attmap = out;                       // 33554432
    float* out_s      = out + 33554432;            // 524288
    float* out_c      = out + 34078720;            // 1048576
    float* out_gs     = out + 35127296;            // 64
    float* out_gc     = out + 35127360;            // 64
    // d_out[0 .. 33.5M) doubles as scratch: outs partials, then sm_rows.

    const dim3 blk(256);

    // 1-2: global context s
    conv3x3_bcr<<<dim3(16, 32, B), blk, 0, stream>>>(xs, nullptr, w_g1, nullptr, g_g1, nullptr, t32, B, 0, 64, 32, H, W);
    gap_kernel<<<dim3(32, B), blk, 0, stream>>>(t32, gs_w, out_gs, 32, HW);
    // 3-4: global context c
    conv3x3_bcr<<<dim3(16, 32, B), blk, 0, stream>>>(xc, nullptr, w_g2, nullptr, g_g2, nullptr, t32, B, 0, 128, 32, H, W);
    gap_kernel<<<dim3(32, B), blk, 0, stream>>>(t32, gc_w, out_gc, 32, HW);
    // 5-6: local fusion convs (const-broadcast channels first) + residual
    conv3x3_bcr<<<dim3(16, 64, B), blk, 0, stream>>>(xs, gs_w, w_ls, b_ls, g_ls, xs, xs1, B, 32, 64, 64, H, W);
    conv3x3_bcr<<<dim3(16, 128, B), blk, 0, stream>>>(xc, gc_w, w_lc, b_lc, g_lc, xc, xc1, B, 32, 128, 128, H, W);
    // 7-8: attention features
    conv3x3_bcr<<<dim3(16, 32, B), blk, 0, stream>>>(xs1, nullptr, w_c1, nullptr, g_c1, nullptr, fs, B, 0, 64, 32, H, W);
    conv3x3_bcr<<<dim3(16, 32, B), blk, 0, stream>>>(xc1, nullptr, w_c2, nullptr, g_c2, nullptr, fc, B, 0, 128, 32, H, W);
    // 9: att = fs^T fc
    att_gemm<<<dim3(16, 256, B), blk, 0, stream>>>(fs, fc, att, N);
    // 10: column stats (softmax over n)
    colstats_part<<<dim3(16, 16, B), blk, 0, stream>>>(att, Mp, Sp, N, 16);
    colstats_comb<<<dim3(16, B), blk, 0, stream>>>(Mp, Sp, Mc, Sc, N, 16);
    // 11: row stats (softmax over m)
    rowstats<<<dim3(N, B), blk, 0, stream>>>(att, Mr, Sr, N);
    // 12: outs = xs1 @ sm_cols  (partials in d_out scratch, then reduce)
    outs_part<<<dim3(16, 8, B), blk, 0, stream>>>(att, xs1, Mc, out_attmap, N, 8);
    outs_reduce<<<dim3((B * 64 * N) / 256), blk, 0, stream>>>(out_attmap, Sc, outs_w, N, 8);
    // 13: materialize sm_rows into d_out scratch
    smr_mat<<<dim3(16 * N, B), blk, 0, stream>>>(att, Mr, Sr, out_attmap, N);
    // 14: outc = xc1 @ sm_rows^T
    outc_gemm<<<dim3(N / 64, 2, B), blk, 0, stream>>>(xc1, out_attmap, outc_w, N);
    // 15: att2 = att + att^T (in place)
    att2_sym<<<dim3(N / 32, N / 32, B), blk, 0, stream>>>(att, N);
    // 16: att2 column stats
    colstats_part<<<dim3(16, 16, B), blk, 0, stream>>>(att, Mp, Sp, N, 16);
    colstats_comb<<<dim3(16, B), blk, 0, stream>>>(Mp, Sp, M2, S2, N, 16);
    // 17: att3 = 2*colsoftmax(att2) (in place; symmetric identity)
    att3_mat<<<dim3(16 * N, B), blk, 0, stream>>>(att, M2, S2, N);
    // 18: att_map = bcr(att3) — 1-channel 3x3 conv on the 4096x4096 map
    conv3x3_bcr<<<dim3(65536, 1, B), blk, 0, stream>>>(att, nullptr, w_oa, nullptr, g_oa, nullptr, out_attmap, B, 0, 1, 1, 4096, 4096);
    // 19-20: output convs + residuals
    conv3x3_bcr<<<dim3(16, 64, B), blk, 0, stream>>>(outs_w, nullptr, w_o1, nullptr, g_o1, xs1, out_s, B, 0, 64, 64, H, W);
    conv3x3_bcr<<<dim3(16, 128, B), blk, 0, stream>>>(outc_w, nullptr, w_o2, nullptr, g_o2, xc1, out_c, B, 0, 128, 128, H, W);
}

// Round 2
// 2302.634 us; speedup vs baseline: 1.1318x; 1.1318x over previous
//
#include <hip/hip_runtime.h>

// AGLI_5703716569604 — round 1: LDS-tiled direct conv for the H=W=64 stages.
// Shapes: B=2, ch1=64, ch2=128, H=W=64, N=4096 (spatial), att is [B,4096,4096].

#define LB __launch_bounds__(256)

constexpr float BN_SCALE = 0.99999500003749968f; // 1/sqrt(1+1e-5)
constexpr float NEG_BIG  = -3.402823466e38f;

// ---------------------------------------------------------------------------
// Tiled 3x3 conv (pad=1) for H=W=64. Block = 16x16 spatial tile, OCT=8 output
// channels per block. Input tile (18x18) staged in LDS per input channel and
// reused across the 8 output-channel accumulators (8-way ILP). Weights are
// read with block-uniform addresses -> scalar loads. Const-broadcast channels
// (global-context gs/gc) folded into a per-block WG[oc][tap] table.
// grid: (16, Cout/8, B), block 256.
__global__ LB void conv3x3_t16(
    const float* __restrict__ in,       // [B, Cin, 64, 64]
    const float* __restrict__ gconst,   // [B, Cg] or nullptr
    const float* __restrict__ w,        // [Cout, Cg+Cin, 3, 3]
    const float* __restrict__ bias,     // [Cout] or nullptr
    const float* __restrict__ bn,       // [2, Cout]
    const float* __restrict__ residual, // [B, Cout, 64, 64] or nullptr
    float* __restrict__ out,
    int Cg, int Cin, int Cout)
{
    constexpr int OCT = 8;
    const int tid = threadIdx.x;
    const int tx = tid & 15, ty = tid >> 4;
    const int x0 = (blockIdx.x & 3) * 16, y0 = (blockIdx.x >> 2) * 16;
    const int oc0 = blockIdx.y * OCT;
    const int b = blockIdx.z;
    const int HW = 4096;
    const int Ct = Cg + Cin;

    __shared__ float tile[18][19];
    __shared__ float wg[OCT][10];

    // fold const-broadcast channels: wg[oc][k] = sum_ic gconst[ic]*w[oc][ic][k]
    if (Cg > 0) {
        for (int e = tid; e < OCT * 9; e += 256) {
            const int oc = e / 9, k = e % 9;
            const float* wq = w + ((long)(oc0 + oc) * Ct) * 9 + k;
            float s = 0.f;
            for (int ic = 0; ic < Cg; ++ic) s += gconst[b * Cg + ic] * wq[ic * 9];
            wg[oc][k] = s;
        }
        __syncthreads();
    }

    float acc[OCT];
    #pragma unroll
    for (int oc = 0; oc < OCT; ++oc) acc[oc] = bias ? bias[oc0 + oc] : 0.f;

    const int x = x0 + tx, y = y0 + ty;
    if (Cg > 0) {
        #pragma unroll
        for (int k = 0; k < 9; ++k) {
            const int dy = k / 3, dx = k % 3;
            if ((unsigned)(y + dy - 1) < 64u && (unsigned)(x + dx - 1) < 64u) {
                #pragma unroll
                for (int oc = 0; oc < OCT; ++oc) acc[oc] += wg[oc][k];
            }
        }
    }

    const float* ib = in + (long)b * Cin * HW;
    for (int ic = 0; ic < Cin; ++ic) {
        __syncthreads();
        #pragma unroll
        for (int r = 0; r < 2; ++r) {
            const int e = tid + r * 256;
            if (e < 324) {
                const int hy = e / 18, hx = e % 18;
                const int yy = y0 + hy - 1, xx = x0 + hx - 1;
                float v = 0.f;
                if ((unsigned)yy < 64u && (unsigned)xx < 64u)
                    v = ib[(long)ic * HW + yy * 64 + xx];
                tile[hy][hx] = v;
            }
        }
        __syncthreads();
        float p[9];
        #pragma unroll
        for (int k = 0; k < 9; ++k) p[k] = tile[ty + k / 3][tx + k % 3];
        const float* wq = w + ((long)oc0 * Ct + (Cg + ic)) * 9;
        #pragma unroll
        for (int oc = 0; oc < OCT; ++oc) {
            #pragma unroll
            for (int k = 0; k < 9; ++k)
                acc[oc] = fmaf(p[k], wq[(long)oc * Ct * 9 + k], acc[oc]);
        }
    }

    const long obase = ((long)b * Cout + oc0) * HW + y * 64 + x;
    #pragma unroll
    for (int oc = 0; oc < OCT; ++oc) {
        const float scale = bn[oc0 + oc] * BN_SCALE;
        const float beta  = bn[Cout + oc0 + oc];
        float v = fmaxf(fmaf(acc[oc], scale, beta), 0.0f);
        const long oidx = obase + (long)oc * HW;
        if (residual) v += residual[oidx];
        out[oidx] = v;
    }
}

// ---------------------------------------------------------------------------
// Generic direct 3x3 conv — retained only for the 1-channel 4096x4096 att_map.
__global__ LB void conv3x3_bcr(
    const float* __restrict__ in, const float* __restrict__ w,
    const float* __restrict__ bn, float* __restrict__ out,
    int B, int H, int W)
{
    const int tid = threadIdx.x;
    const long HW = (long)H * W;
    const long hw = (long)blockIdx.x * 256 + tid;
    if (hw >= HW) return;
    const int b = blockIdx.z;
    const int x = (int)(hw % W);
    const int y = (int)(hw / W);
    float acc = 0.0f;
    const float* ip = in + (long)b * HW;
    #pragma unroll
    for (int dy = 0; dy < 3; ++dy) {
        const int yy = y + dy - 1;
        if (yy < 0 || yy >= H) continue;
        #pragma unroll
        for (int dx = 0; dx < 3; ++dx) {
            const int xx = x + dx - 1;
            if (xx < 0 || xx >= W) continue;
            acc = fmaf(w[dy * 3 + dx], ip[(long)yy * W + xx], acc);
        }
    }
    const float scale = bn[0] * BN_SCALE;
    const float beta  = bn[1];
    out[(long)b * HW + hw] = fmaxf(fmaf(acc, scale, beta), 0.0f);
}

// ---------------------------------------------------------------------------
// Global average pool of [B,C,HW] -> writes mean to two destinations [B,C].
__global__ LB void gap_kernel(const float* __restrict__ in,
                              float* __restrict__ o1, float* __restrict__ o2,
                              int C, int HW)
{
    const int c = blockIdx.x, b = blockIdx.y;
    const float* p = in + ((long)b * C + c) * HW;
    float s = 0.f;
    for (int i = threadIdx.x; i < HW; i += 256) s += p[i];
    #pragma unroll
    for (int off = 32; off; off >>= 1) s += __shfl_down(s, off);
    __shared__ float red[4];
    if ((threadIdx.x & 63) == 0) red[threadIdx.x >> 6] = s;
    __syncthreads();
    if (threadIdx.x == 0) {
        const float t = (red[0] + red[1] + red[2] + red[3]) / (float)HW;
        o1[b * C + c] = t;
        o2[b * C + c] = t;
    }
}

// ---------------------------------------------------------------------------
// att[b,n,m] = sum_c fs[b,c,n] * fc[b,c,m], C=32.
__global__ LB void att_gemm(const float* __restrict__ fs, const float* __restrict__ fc,
                            float* __restrict__ att, int N)
{
    __shared__ float lfs[32][17];
    const int tid = threadIdx.x;
    const int m  = blockIdx.x * 256 + tid;
    const int n0 = blockIdx.y * 16;
    const int b  = blockIdx.z;
    for (int i = tid; i < 32 * 16; i += 256) {
        const int c = i >> 4, nn = i & 15;
        lfs[c][nn] = fs[((long)b * 32 + c) * N + n0 + nn];
    }
    __syncthreads();
    float acc[16];
    #pragma unroll
    for (int i = 0; i < 16; ++i) acc[i] = 0.f;
    const float* fcp = fc + (long)b * 32 * N + m;
    #pragma unroll
    for (int c = 0; c < 32; ++c) {
        const float f = fcp[(long)c * N];
        #pragma unroll
        for (int nn = 0; nn < 16; ++nn) acc[nn] = fmaf(lfs[c][nn], f, acc[nn]);
    }
    float* op = att + ((long)b * N + n0) * N + m;
    #pragma unroll
    for (int nn = 0; nn < 16; ++nn) op[(long)nn * N] = acc[nn];
}

// ---------------------------------------------------------------------------
// Column-wise online (max, sum-exp) over an n-chunk. grid: (N/256, S, B)
__global__ LB void colstats_part(const float* __restrict__ att,
                                 float* __restrict__ Mp, float* __restrict__ Sp,
                                 int N, int S)
{
    const int m = blockIdx.x * 256 + threadIdx.x;
    const int s = blockIdx.y, b = blockIdx.z;
    const int chunk = N / S;
    const float* p = att + (long)b * N * N + (long)s * chunk * N + m;
    float mx = NEG_BIG, sum = 0.f;
    for (int n = 0; n < chunk; ++n) {
        const float v = p[(long)n * N];
        if (v > mx) { sum = sum * __expf(mx - v) + 1.f; mx = v; }
        else        { sum += __expf(v - mx); }
    }
    Mp[((long)b * S + s) * N + m] = mx;
    Sp[((long)b * S + s) * N + m] = sum;
}

// grid: (N/256, B)
__global__ LB void colstats_comb(const float* __restrict__ Mp, const float* __restrict__ Sp,
                                 float* __restrict__ M, float* __restrict__ Sm,
                                 int N, int S)
{
    const int m = blockIdx.x * 256 + threadIdx.x;
    const int b = blockIdx.y;
    float mx = NEG_BIG, sum = 0.f;
    for (int s = 0; s < S; ++s) {
        const float m2 = Mp[((long)b * S + s) * N + m];
        const float s2 = Sp[((long)b * S + s) * N + m];
        const float mn = fmaxf(mx, m2);
        sum = sum * __expf(mx - mn) + s2 * __expf(m2 - mn);
        mx = mn;
    }
    M[(long)b * N + m]  = mx;
    Sm[(long)b * N + m] = sum;
}

// ---------------------------------------------------------------------------
// Row-wise (max, sum-exp). grid: (N, B), block 256
__global__ LB void rowstats(const float* __restrict__ att,
                            float* __restrict__ Mr, float* __restrict__ Sr, int N)
{
    const int n = blockIdx.x, b = blockIdx.y;
    const float* p = att + ((long)b * N + n) * N;
    float mx = NEG_BIG, sum = 0.f;
    for (int m = threadIdx.x; m < N; m += 256) {
        const float v = p[m];
        if (v > mx) { sum = sum * __expf(mx - v) + 1.f; mx = v; }
        else        { sum += __expf(v - mx); }
    }
    #pragma unroll
    for (int off = 32; off; off >>= 1) {
        const float m2 = __shfl_down(mx, off);
        const float s2 = __shfl_down(sum, off);
        const float mn = fmaxf(mx, m2);
        sum = sum * __expf(mx - mn) + s2 * __expf(m2 - mn);
        mx = mn;
    }
    __shared__ float rm[4], rs[4];
    const int lane = threadIdx.x & 63, wv = threadIdx.x >> 6;
    if (lane == 0) { rm[wv] = mx; rs[wv] = sum; }
    __syncthreads();
    if (threadIdx.x == 0) {
        mx = rm[0]; sum = rs[0];
        for (int w = 1; w < 4; ++w) {
            const float mn = fmaxf(mx, rm[w]);
            sum = sum * __expf(mx - mn) + rs[w] * __expf(rm[w] - mn);
            mx = mn;
        }
        Mr[(long)b * N + n] = mx;
        Sr[(long)b * N + n] = sum;
    }
}

// ---------------------------------------------------------------------------
// outs partial: part[b,s,c,m] = sum_{n in chunk s} xs1[b,c,n]*exp(att[n,m]-Mc[m])
// grid: (N/256, S, B); C=64 fixed.
__global__ LB void outs_part(const float* __restrict__ att, const float* __restrict__ xs1,
                             const float* __restrict__ Mc, float* __restrict__ part,
                             int N, int S)
{
    __shared__ float lxt[64][68];
    const int tid = threadIdx.x;
    const int m = blockIdx.x * 256 + tid;
    const int s = blockIdx.y, b = blockIdx.z;
    const int chunk = N / S;
    float acc[64];
    #pragma unroll
    for (int c = 0; c < 64; ++c) acc[c] = 0.f;
    const float mcv = Mc[(long)b * N + m];
    const float* attb = att + (long)b * N * N + m;
    const float* xb = xs1 + (long)b * 64 * N;
    for (int n0 = s * chunk; n0 < (s + 1) * chunk; n0 += 64) {
        __syncthreads();
        #pragma unroll
        for (int i = 0; i < 16; ++i) {
            const int e = tid + i * 256;
            const int c = e >> 6, nn = e & 63;
            lxt[nn][c] = xb[(long)c * N + n0 + nn];
        }
        __syncthreads();
        for (int nn = 0; nn < 64; ++nn) {
            const float ev = __expf(attb[(long)(n0 + nn) * N] - mcv);
            #pragma unroll
            for (int c4 = 0; c4 < 16; ++c4) {
                const float4 xv = *(const float4*)&lxt[nn][c4 * 4];
                acc[c4 * 4 + 0] = fmaf(xv.x, ev, acc[c4 * 4 + 0]);
                acc[c4 * 4 + 1] = fmaf(xv.y, ev, acc[c4 * 4 + 1]);
                acc[c4 * 4 + 2] = fmaf(xv.z, ev, acc[c4 * 4 + 2]);
                acc[c4 * 4 + 3] = fmaf(xv.w, ev, acc[c4 * 4 + 3]);
            }
        }
    }
    float* pp = part + ((long)(b * S + s) * 64) * N + m;
    #pragma unroll
    for (int c = 0; c < 64; ++c) pp[(long)c * N] = acc[c];
}

// grid: (B*64*N/256). N==4096 assumed (shifts).
__global__ LB void outs_reduce(const float* __restrict__ part, const float* __restrict__ Sc,
                               float* __restrict__ outs, int N, int S)
{
    const long idx = (long)blockIdx.x * 256 + threadIdx.x;
    const int m = (int)(idx & (long)(N - 1));
    const long bc = idx >> 12;
    const int c = (int)(bc & 63);
    const int b = (int)(bc >> 6);
    float s = 0.f;
    for (int ss = 0; ss < S; ++ss)
        s += part[((long)(b * S + ss) * 64 + c) * N + m];
    outs[idx] = s / Sc[(long)b * N + m];
}

// ---------------------------------------------------------------------------
// Materialize row-softmax: smr[b,n,m] = exp(att - Mr[n]) / Sr[n].
__global__ LB void smr_mat(const float* __restrict__ att, const float* __restrict__ Mr,
                           const float* __restrict__ Sr, float* __restrict__ smr, int N)
{
    const int b = blockIdx.y;
    const int n = blockIdx.x >> 4;
    const int m = ((blockIdx.x & 15) << 8) + threadIdx.x;
    const long idx = ((long)b * N + n) * N + m;
    smr[idx] = __expf(att[idx] - Mr[(long)b * N + n]) / Sr[(long)b * N + n];
}

// ---------------------------------------------------------------------------
// outc[b,c,j] = sum_m xc1[b,c,m] * smr[b,j,m]   (C = A·B^T), Cch=128.
__global__ LB void outc_gemm(const float* __restrict__ A, const float* __restrict__ Bm,
                             float* __restrict__ C, int N)
{
    __shared__ float aT[32][68];
    __shared__ float bT[32][68];
    const int tid = threadIdx.x;
    const int j0 = blockIdx.x * 64, c0 = blockIdx.y * 64, b = blockIdx.z;
    const int tx = tid & 15, ty = tid >> 4;
    float acc[4][4];
    #pragma unroll
    for (int i = 0; i < 4; ++i)
        #pragma unroll
        for (int k = 0; k < 4; ++k) acc[i][k] = 0.f;
    const float* Ab = A + ((long)b * 128 + c0) * N;
    const float* Bb = Bm + ((long)b * N + j0) * N;
    for (int m0 = 0; m0 < N; m0 += 32) {
        __syncthreads();
        #pragma unroll
        for (int i = 0; i < 8; ++i) {
            const int e = tid + i * 256;
            const int row = e >> 5, col = e & 31;
            aT[col][row] = Ab[(long)row * N + m0 + col];
            bT[col][row] = Bb[(long)row * N + m0 + col];
        }
        __syncthreads();
        #pragma unroll
        for (int mm = 0; mm < 32; ++mm) {
            const float4 av = *(const float4*)&aT[mm][ty << 2];
            const float4 bv = *(const float4*)&bT[mm][tx << 2];
            const float a[4] = {av.x, av.y, av.z, av.w};
            const float bb[4] = {bv.x, bv.y, bv.z, bv.w};
            #pragma unroll
            for (int i = 0; i < 4; ++i)
                #pragma unroll
                for (int k = 0; k < 4; ++k)
                    acc[i][k] = fmaf(a[i], bb[k], acc[i][k]);
        }
    }
    #pragma unroll
    for (int i = 0; i < 4; ++i) {
        float* cp = C + ((long)b * 128 + c0 + (ty << 2) + i) * N + j0 + (tx << 2);
        *(float4*)cp = make_float4(acc[i][0], acc[i][1], acc[i][2], acc[i][3]);
    }
}

// ---------------------------------------------------------------------------
// In-place att += att^T via 32x32 tile pairs. grid: (N/32, N/32, B); ti<=tj.
__global__ LB void att2_sym(float* __restrict__ att, int N)
{
    const int ti = blockIdx.x, tj = blockIdx.y;
    if (ti > tj) return;
    const int b = blockIdx.z;
    __shared__ float Ta[32][33], Tb[32][33];
    const long base = (long)b * N * N;
    const int tid = threadIdx.x;
    const int r = tid >> 5, col = tid & 31;
    #pragma unroll
    for (int i = 0; i < 4; ++i) {
        const int rr = r + i * 8;
        Ta[rr][col] = att[base + (long)(ti * 32 + rr) * N + tj * 32 + col];
        Tb[rr][col] = att[base + (long)(tj * 32 + rr) * N + ti * 32 + col];
    }
    __syncthreads();
    #pragma unroll
    for (int i = 0; i < 4; ++i) {
        const int rr = r + i * 8;
        att[base + (long)(ti * 32 + rr) * N + tj * 32 + col] = Ta[rr][col] + Tb[col][rr];
        if (ti != tj)
            att[base + (long)(tj * 32 + rr) * N + ti * 32 + col] = Tb[rr][col] + Ta[col][rr];
    }
}

// ---------------------------------------------------------------------------
// In-place att3 = 2*exp(att2 - M2[m]) / S2[m]. grid: (16*N, B).
__global__ LB void att3_mat(float* __restrict__ att, const float* __restrict__ M2,
                            const float* __restrict__ S2, int N)
{
    const int b = blockIdx.y;
    const int n = blockIdx.x >> 4;
    const int m = ((blockIdx.x & 15) << 8) + threadIdx.x;
    const long idx = ((long)b * N + n) * N + m;
    att[idx] = 2.f * __expf(att[idx] - M2[(long)b * N + m]) / S2[(long)b * N + m];
}

// ===========================================================================
extern "C" void kernel_launch(void* const* d_in, const int* in_sizes, int n_in,
                              void* d_out, int out_size, void* d_ws, size_t ws_size,
                              hipStream_t stream)
{
    const float* xs   = (const float*)d_in[0];
    const float* xc   = (const float*)d_in[1];
    const float* w_g1 = (const float*)d_in[2];
    const float* g_g1 = (const float*)d_in[3];
    const float* w_g2 = (const float*)d_in[4];
    const float* g_g2 = (const float*)d_in[5];
    const float* w_ls = (const float*)d_in[6];
    const float* b_ls = (const float*)d_in[7];
    const float* g_ls = (const float*)d_in[8];
    const float* w_lc = (const float*)d_in[9];
    const float* b_lc = (const float*)d_in[10];
    const float* g_lc = (const float*)d_in[11];
    const float* w_c1 = (const float*)d_in[12];
    const float* g_c1 = (const float*)d_in[13];
    const float* w_c2 = (const float*)d_in[14];
    const float* g_c2 = (const float*)d_in[15];
    const float* w_o1 = (const float*)d_in[16];
    const float* g_o1 = (const float*)d_in[17];
    const float* w_o2 = (const float*)d_in[18];
    const float* g_o2 = (const float*)d_in[19];
    const float* w_oa = (const float*)d_in[20];
    const float* g_oa = (const float*)d_in[21];

    const int B = 2, HW = 4096, N = 4096;

    // ---- workspace layout (float offsets) ----
    float* ws = (float*)d_ws;
    float* xs1    = ws;                       // 524288
    float* xc1    = ws + 524288;              // 1048576
    float* fs     = ws + 1572864;             // 262144
    float* fc     = ws + 1835008;             // 262144
    float* t32    = ws + 2097152;             // 262144
    float* outs_w = ws + 2359296;             // 524288
    float* outc_w = ws + 2883584;             // 1048576
    float* gs_w   = ws + 3932160;             // 64
    float* gc_w   = ws + 3932224;             // 64
    float* Mc     = ws + 3932288;             // 8192
    float* Sc     = ws + 3940480;             // 8192
    float* Mr     = ws + 3948672;             // 8192
    float* Sr     = ws + 3956864;             // 8192
    float* M2     = ws + 3965056;             // 8192
    float* S2     = ws + 3973248;             // 8192
    float* Mp     = ws + 3981440;             // 131072 (B*16*N)
    float* Sp     = ws + 4112512;             // 131072
    float* att    = ws + 4243584;             // 33554432

    // ---- d_out layout ----
    float* out = (float*)d_out;
    float* out_attmap = out;                       // 33554432
    float* out_s      = out + 33554432;            // 524288
    float* out_c      = out + 34078720;            // 1048576
    float* out_gs     = out + 35127296;            // 64
    float* out_gc     = out + 35127360;            // 64

    const dim3 blk(256);

    // 1-2: global context s
    conv3x3_t16<<<dim3(16, 4, B), blk, 0, stream>>>(xs, nullptr, w_g1, nullptr, g_g1, nullptr, t32, 0, 64, 32);
    gap_kernel<<<dim3(32, B), blk, 0, stream>>>(t32, gs_w, out_gs, 32, HW);
    // 3-4: global context c
    conv3x3_t16<<<dim3(16, 4, B), blk, 0, stream>>>(xc, nullptr, w_g2, nullptr, g_g2, nullptr, t32, 0, 128, 32);
    gap_kernel<<<dim3(32, B), blk, 0, stream>>>(t32, gc_w, out_gc, 32, HW);
    // 5-6: local fusion convs (const-broadcast channels) + residual
    conv3x3_t16<<<dim3(16, 8, B), blk, 0, stream>>>(xs, gs_w, w_ls, b_ls, g_ls, xs, xs1, 32, 64, 64);
    conv3x3_t16<<<dim3(16, 16, B), blk, 0, stream>>>(xc, gc_w, w_lc, b_lc, g_lc, xc, xc1, 32, 128, 128);
    // 7-8: attention features
    conv3x3_t16<<<dim3(16, 4, B), blk, 0, stream>>>(xs1, nullptr, w_c1, nullptr, g_c1, nullptr, fs, 0, 64, 32);
    conv3x3_t16<<<dim3(16, 4, B), blk, 0, stream>>>(xc1, nullptr, w_c2, nullptr, g_c2, nullptr, fc, 0, 128, 32);
    // 9: att = fs^T fc
    att_gemm<<<dim3(16, 256, B), blk, 0, stream>>>(fs, fc, att, N);
    // 10: column stats (softmax over n)
    colstats_part<<<dim3(16, 16, B), blk, 0, stream>>>(att, Mp, Sp, N, 16);
    colstats_comb<<<dim3(16, B), blk, 0, stream>>>(Mp, Sp, Mc, Sc, N, 16);
    // 11: row stats (softmax over m)
    rowstats<<<dim3(N, B), blk, 0, stream>>>(att, Mr, Sr, N);
    // 12: outs = xs1 @ sm_cols  (partials in d_out scratch, then reduce)
    outs_part<<<dim3(16, 8, B), blk, 0, stream>>>(att, xs1, Mc, out_attmap, N, 8);
    outs_reduce<<<dim3((B * 64 * N) / 256), blk, 0, stream>>>(out_attmap, Sc, outs_w, N, 8);
    // 13: materialize sm_rows into d_out scratch
    smr_mat<<<dim3(16 * N, B), blk, 0, stream>>>(att, Mr, Sr, out_attmap, N);
    // 14: outc = xc1 @ sm_rows^T
    outc_gemm<<<dim3(N / 64, 2, B), blk, 0, stream>>>(xc1, out_attmap, outc_w, N);
    // 15: att2 = att + att^T (in place)
    att2_sym<<<dim3(N / 32, N / 32, B), blk, 0, stream>>>(att, N);
    // 16: att2 column stats
    colstats_part<<<dim3(16, 16, B), blk, 0, stream>>>(att, Mp, Sp, N, 16);
    colstats_comb<<<dim3(16, B), blk, 0, stream>>>(Mp, Sp, M2, S2, N, 16);
    // 17: att3 = 2*colsoftmax(att2) (in place; symmetric identity)
    att3_mat<<<dim3(16 * N, B), blk, 0, stream>>>(att, M2, S2, N);
    // 18: att_map = bcr(att3) — 1-channel 3x3 conv on the 4096x4096 map
    conv3x3_bcr<<<dim3(65536, 1, B), blk, 0, stream>>>(att, w_oa, g_oa, out_attmap, B, 4096, 4096);
    // 19-20: output convs + residuals
    conv3x3_t16<<<dim3(16, 8, B), blk, 0, stream>>>(outs_w, nullptr, w_o1, nullptr, g_o1, xs1, out_s, 0, 64, 64);
    conv3x3_t16<<<dim3(16, 16, B), blk, 0, stream>>>(outc_w, nullptr, w_o2, nullptr, g_o2, xc1, out_c, 0, 128, 128);
}

// Round 3
// 2203.202 us; speedup vs baseline: 1.1829x; 1.0451x over previous
//
#include <hip/hip_runtime.h>

// AGLI_5703716569604 — round 2: restructure all att-matrix stages.
// B=2, ch1=64, ch2=128, H=W=64, N=4096, att [B,4096,4096].

#define LB __launch_bounds__(256)

constexpr float BN_SCALE = 0.99999500003749968f; // 1/sqrt(1+1e-5)
constexpr float NEG_BIG  = -3.402823466e38f;

// ---------------------------------------------------------------------------
// Tiled 3x3 conv (pad=1) for H=W=64 stages (unchanged from round 1).
__global__ LB void conv3x3_t16(
    const float* __restrict__ in, const float* __restrict__ gconst,
    const float* __restrict__ w, const float* __restrict__ bias,
    const float* __restrict__ bn, const float* __restrict__ residual,
    float* __restrict__ out, int Cg, int Cin, int Cout)
{
    constexpr int OCT = 8;
    const int tid = threadIdx.x;
    const int tx = tid & 15, ty = tid >> 4;
    const int x0 = (blockIdx.x & 3) * 16, y0 = (blockIdx.x >> 2) * 16;
    const int oc0 = blockIdx.y * OCT;
    const int b = blockIdx.z;
    const int HW = 4096;
    const int Ct = Cg + Cin;

    __shared__ float tile[18][19];
    __shared__ float wg[OCT][10];

    if (Cg > 0) {
        for (int e = tid; e < OCT * 9; e += 256) {
            const int oc = e / 9, k = e % 9;
            const float* wq = w + ((long)(oc0 + oc) * Ct) * 9 + k;
            float s = 0.f;
            for (int ic = 0; ic < Cg; ++ic) s += gconst[b * Cg + ic] * wq[ic * 9];
            wg[oc][k] = s;
        }
        __syncthreads();
    }

    float acc[OCT];
    #pragma unroll
    for (int oc = 0; oc < OCT; ++oc) acc[oc] = bias ? bias[oc0 + oc] : 0.f;

    const int x = x0 + tx, y = y0 + ty;
    if (Cg > 0) {
        #pragma unroll
        for (int k = 0; k < 9; ++k) {
            const int dy = k / 3, dx = k % 3;
            if ((unsigned)(y + dy - 1) < 64u && (unsigned)(x + dx - 1) < 64u) {
                #pragma unroll
                for (int oc = 0; oc < OCT; ++oc) acc[oc] += wg[oc][k];
            }
        }
    }

    const float* ib = in + (long)b * Cin * HW;
    for (int ic = 0; ic < Cin; ++ic) {
        __syncthreads();
        #pragma unroll
        for (int r = 0; r < 2; ++r) {
            const int e = tid + r * 256;
            if (e < 324) {
                const int hy = e / 18, hx = e % 18;
                const int yy = y0 + hy - 1, xx = x0 + hx - 1;
                float v = 0.f;
                if ((unsigned)yy < 64u && (unsigned)xx < 64u)
                    v = ib[(long)ic * HW + yy * 64 + xx];
                tile[hy][hx] = v;
            }
        }
        __syncthreads();
        float p[9];
        #pragma unroll
        for (int k = 0; k < 9; ++k) p[k] = tile[ty + k / 3][tx + k % 3];
        const float* wq = w + ((long)oc0 * Ct + (Cg + ic)) * 9;
        #pragma unroll
        for (int oc = 0; oc < OCT; ++oc) {
            #pragma unroll
            for (int k = 0; k < 9; ++k)
                acc[oc] = fmaf(p[k], wq[(long)oc * Ct * 9 + k], acc[oc]);
        }
    }

    const long obase = ((long)b * Cout + oc0) * HW + y * 64 + x;
    #pragma unroll
    for (int oc = 0; oc < OCT; ++oc) {
        const float scale = bn[oc0 + oc] * BN_SCALE;
        const float beta  = bn[Cout + oc0 + oc];
        float v = fmaxf(fmaf(acc[oc], scale, beta), 0.0f);
        const long oidx = obase + (long)oc * HW;
        if (residual) v += residual[oidx];
        out[oidx] = v;
    }
}

// ---------------------------------------------------------------------------
__global__ LB void gap_kernel(const float* __restrict__ in,
                              float* __restrict__ o1, float* __restrict__ o2,
                              int C, int HW)
{
    const int c = blockIdx.x, b = blockIdx.y;
    const float* p = in + ((long)b * C + c) * HW;
    float s = 0.f;
    for (int i = threadIdx.x; i < HW; i += 256) s += p[i];
    #pragma unroll
    for (int off = 32; off; off >>= 1) s += __shfl_down(s, off);
    __shared__ float red[4];
    if ((threadIdx.x & 63) == 0) red[threadIdx.x >> 6] = s;
    __syncthreads();
    if (threadIdx.x == 0) {
        const float t = (red[0] + red[1] + red[2] + red[3]) / (float)HW;
        o1[b * C + c] = t;
        o2[b * C + c] = t;
    }
}

// ---------------------------------------------------------------------------
// att[b,n,m] = sum_c fs[b,c,n] * fc[b,c,m], C=32.
__global__ LB void att_gemm(const float* __restrict__ fs, const float* __restrict__ fc,
                            float* __restrict__ att, int N)
{
    __shared__ float lfs[32][17];
    const int tid = threadIdx.x;
    const int m  = blockIdx.x * 256 + tid;
    const int n0 = blockIdx.y * 16;
    const int b  = blockIdx.z;
    for (int i = tid; i < 32 * 16; i += 256) {
        const int c = i >> 4, nn = i & 15;
        lfs[c][nn] = fs[((long)b * 32 + c) * N + n0 + nn];
    }
    __syncthreads();
    float acc[16];
    #pragma unroll
    for (int i = 0; i < 16; ++i) acc[i] = 0.f;
    const float* fcp = fc + (long)b * 32 * N + m;
    #pragma unroll
    for (int c = 0; c < 32; ++c) {
        const float f = fcp[(long)c * N];
        #pragma unroll
        for (int nn = 0; nn < 16; ++nn) acc[nn] = fmaf(lfs[c][nn], f, acc[nn]);
    }
    float* op = att + ((long)b * N + n0) * N + m;
    #pragma unroll
    for (int nn = 0; nn < 16; ++nn) op[(long)nn * N] = acc[nn];
}

// ---------------------------------------------------------------------------
// Transpose [C,N] -> [N,C] per batch. grid (N/32, C/32, B), block 256.
__global__ LB void transpose_cn(const float* __restrict__ in, float* __restrict__ outT,
                                int C, int N)
{
    __shared__ float t[32][33];
    const int tid = threadIdx.x;
    const int cx = tid & 31, ry = tid >> 5;
    const int n0 = blockIdx.x * 32, c0 = blockIdx.y * 32, b = blockIdx.z;
    const float* ip = in + (long)b * C * N;
    #pragma unroll
    for (int i = 0; i < 4; ++i)
        t[ry + i * 8][cx] = ip[(long)(c0 + ry + i * 8) * N + n0 + cx];
    __syncthreads();
    float* op = outT + (long)b * N * C;
    #pragma unroll
    for (int i = 0; i < 4; ++i)
        op[(long)(n0 + ry + i * 8) * C + c0 + cx] = t[cx][ry + i * 8];
}

// ---------------------------------------------------------------------------
// Column-wise online (max, sum-exp) over an n-chunk. grid: (N/256, S, B)
__global__ LB void colstats_part(const float* __restrict__ att,
                                 float* __restrict__ Mp, float* __restrict__ Sp,
                                 int N, int S)
{
    const int m = blockIdx.x * 256 + threadIdx.x;
    const int s = blockIdx.y, b = blockIdx.z;
    const int chunk = N / S;
    const float* p = att + (long)b * N * N + (long)s * chunk * N + m;
    float mx = NEG_BIG, sum = 0.f;
    for (int n = 0; n < chunk; ++n) {
        const float v = p[(long)n * N];
        if (v > mx) { sum = sum * __expf(mx - v) + 1.f; mx = v; }
        else        { sum += __expf(v - mx); }
    }
    Mp[((long)b * S + s) * N + m] = mx;
    Sp[((long)b * S + s) * N + m] = sum;
}

// grid: (N/256, B); combines S partial (max,sumexp) sets.
__global__ LB void colstats_comb(const float* __restrict__ Mp, const float* __restrict__ Sp,
                                 float* __restrict__ M, float* __restrict__ Sm,
                                 int N, int S)
{
    const int m = blockIdx.x * 256 + threadIdx.x;
    const int b = blockIdx.y;
    float mx = NEG_BIG, sum = 0.f;
    for (int s = 0; s < S; ++s) {
        const float m2 = Mp[((long)b * S + s) * N + m];
        const float s2 = Sp[((long)b * S + s) * N + m];
        const float mn = fmaxf(mx, m2);
        sum = sum * __expf(mx - mn) + s2 * __expf(m2 - mn);
        mx = mn;
    }
    M[(long)b * N + m]  = mx;
    Sm[(long)b * N + m] = sum;
}

// ---------------------------------------------------------------------------
// Row-wise (max, sum-exp). grid: (N, B), block 256
__global__ LB void rowstats(const float* __restrict__ att,
                            float* __restrict__ Mr, float* __restrict__ Sr, int N)
{
    const int n = blockIdx.x, b = blockIdx.y;
    const float* p = att + ((long)b * N + n) * N;
    float mx = NEG_BIG, sum = 0.f;
    for (int m = threadIdx.x; m < N; m += 256) {
        const float v = p[m];
        if (v > mx) { sum = sum * __expf(mx - v) + 1.f; mx = v; }
        else        { sum += __expf(v - mx); }
    }
    #pragma unroll
    for (int off = 32; off; off >>= 1) {
        const float m2 = __shfl_down(mx, off);
        const float s2 = __shfl_down(sum, off);
        const float mn = fmaxf(mx, m2);
        sum = sum * __expf(mx - mn) + s2 * __expf(m2 - mn);
        mx = mn;
    }
    __shared__ float rm[4], rs[4];
    const int lane = threadIdx.x & 63, wv = threadIdx.x >> 6;
    if (lane == 0) { rm[wv] = mx; rs[wv] = sum; }
    __syncthreads();
    if (threadIdx.x == 0) {
        mx = rm[0]; sum = rs[0];
        for (int w = 1; w < 4; ++w) {
            const float mn = fmaxf(mx, rm[w]);
            sum = sum * __expf(mx - mn) + rs[w] * __expf(rm[w] - mn);
            mx = mn;
        }
        Mr[(long)b * N + n] = mx;
        Sr[(long)b * N + n] = sum;
    }
}

// ---------------------------------------------------------------------------
// outs partial with uniform-operand FMA (no LDS):
// part[b,s,c,m] = sum_{n in chunk} xs1T[n,c] * exp(att[n,m]-Mc[m])
// grid: (16, S=32, B), block 256. xs1T: [B,N,64].
__global__ LB void outs_part2(const float* __restrict__ att,
                              const float* __restrict__ xs1T,
                              const float* __restrict__ Mc,
                              float* __restrict__ part, int N, int S)
{
    const int tid = threadIdx.x;
    const int m = blockIdx.x * 256 + tid;
    const int s = blockIdx.y, b = blockIdx.z;
    const int chunk = N / S;
    float acc[64];
    #pragma unroll
    for (int c = 0; c < 64; ++c) acc[c] = 0.f;
    const float mcv = Mc[(long)b * N + m];
    const float* ap = att + (long)b * N * N + (long)s * chunk * N + m;
    const float* xp = xs1T + ((long)b * N + (long)s * chunk) * 64;
    for (int n = 0; n < chunk; ++n) {
        const float ev = __expf(ap[(long)n * N] - mcv);
        const float* xr = xp + n * 64;  // wave-uniform address
        #pragma unroll
        for (int c = 0; c < 64; ++c) acc[c] = fmaf(xr[c], ev, acc[c]);
    }
    float* pp = part + ((long)(b * S + s) * 64) * N + m;
    #pragma unroll
    for (int c = 0; c < 64; ++c) pp[(long)c * N] = acc[c];
}

// grid: (B*64*N/256). Sums S partials and divides by Sc.
__global__ LB void outs_reduce(const float* __restrict__ part, const float* __restrict__ Sc,
                               float* __restrict__ outs, int N, int S)
{
    const long idx = (long)blockIdx.x * 256 + threadIdx.x;
    const int m = (int)(idx & (long)(N - 1));
    const long bc = idx >> 12;
    const int c = (int)(bc & 63);
    const int b = (int)(bc >> 6);
    float s = 0.f;
    for (int ss = 0; ss < S; ++ss)
        s += part[((long)(b * S + ss) * 64 + c) * N + m];
    outs[idx] = s / Sc[(long)b * N + m];
}

// ---------------------------------------------------------------------------
// outc partial, row-softmax fused into tile load:
// part[b,sm,c,j] = sum_{m in chunk} xc1T[m,c] * exp(att[j,m]-Mr[j])
// grid: (64 j-tiles, SM=8, B), block 256 (4 c-groups x 64 j). xc1T: [B,N,128].
__global__ LB void outc_part(const float* __restrict__ att,
                             const float* __restrict__ xc1T,
                             const float* __restrict__ Mr,
                             float* __restrict__ part, int N, int SM)
{
    __shared__ float ev[64][65];
    __shared__ float mr_s[64];
    const int tid = threadIdx.x;
    const int jl = tid & 63, cg = tid >> 6;
    const int j0 = blockIdx.x * 64;
    const int sm = blockIdx.y, b = blockIdx.z;
    const int chunk = N / SM;
    if (tid < 64) mr_s[tid] = Mr[(long)b * N + j0 + tid];
    __syncthreads();
    float acc[32];
    #pragma unroll
    for (int c = 0; c < 32; ++c) acc[c] = 0.f;
    const float* ab = att + ((long)b * N + j0) * N;
    const float* xb = xc1T + (long)b * N * 128;
    for (int m0 = sm * chunk; m0 < (sm + 1) * chunk; m0 += 64) {
        __syncthreads();
        #pragma unroll
        for (int i = 0; i < 16; ++i) {
            const int e = tid + i * 256;
            const int r = e >> 6, cc = e & 63;
            ev[r][cc] = __expf(ab[(long)r * N + m0 + cc] - mr_s[r]);
        }
        __syncthreads();
        for (int mm = 0; mm < 64; ++mm) {
            const float e = ev[jl][mm];
            const float* xr = xb + (long)(m0 + mm) * 128 + cg * 32; // wave-uniform
            #pragma unroll
            for (int c = 0; c < 32; ++c) acc[c] = fmaf(xr[c], e, acc[c]);
        }
    }
    float* pp = part + ((long)(b * SM + sm) * 128 + cg * 32) * N + j0 + jl;
    #pragma unroll
    for (int c = 0; c < 32; ++c) pp[(long)c * N] = acc[c];
}

// grid: (B*128*N/256). Sums SM partials and divides by Sr[j].
__global__ LB void outc_reduce(const float* __restrict__ part, const float* __restrict__ Sr,
                               float* __restrict__ outc, int N, int SM)
{
    const long idx = (long)blockIdx.x * 256 + threadIdx.x;
    const int j = (int)(idx & (long)(N - 1));
    const long bc = idx >> 12;
    const int c = (int)(bc & 127);
    const int b = (int)(bc >> 7);
    float s = 0.f;
    for (int ss = 0; ss < SM; ++ss)
        s += part[((long)(b * SM + ss) * 128 + c) * N + j];
    outc[idx] = s / Sr[(long)b * N + j];
}

// ---------------------------------------------------------------------------
// In-place att += att^T AND per-tile-row column stats of the result.
// grid: (N/32, N/32, B); ti<=tj do work. Mp2/Sp2: [B,128,N].
__global__ LB void att2_sym_stats(float* __restrict__ att,
                                  float* __restrict__ Mp2, float* __restrict__ Sp2, int N)
{
    const int ti = blockIdx.x, tj = blockIdx.y;
    if (ti > tj) return;
    const int b = blockIdx.z;
    __shared__ float Ta[32][33], Tb[32][33];
    __shared__ float pm[8][33], ps[8][33];
    const long base = (long)b * N * N;
    const int tid = threadIdx.x;
    const int r = tid >> 5, col = tid & 31;
    #pragma unroll
    for (int i = 0; i < 4; ++i) {
        const int rr = r + i * 8;
        Ta[rr][col] = att[base + (long)(ti * 32 + rr) * N + tj * 32 + col];
        Tb[rr][col] = att[base + (long)(tj * 32 + rr) * N + ti * 32 + col];
    }
    __syncthreads();
    float va[4], vb[4];
    #pragma unroll
    for (int i = 0; i < 4; ++i) {
        const int rr = r + i * 8;
        va[i] = Ta[rr][col] + Tb[col][rr];
        att[base + (long)(ti * 32 + rr) * N + tj * 32 + col] = va[i];
        if (ti != tj) {
            vb[i] = Tb[rr][col] + Ta[col][rr];
            att[base + (long)(tj * 32 + rr) * N + ti * 32 + col] = vb[i];
        }
    }
    // stats for tile (ti,tj): columns tj*32+col, rows over this 32-row stripe
    float mx = NEG_BIG, sm = 0.f;
    #pragma unroll
    for (int i = 0; i < 4; ++i) {
        const float v = va[i];
        const float mn = fmaxf(mx, v);
        sm = sm * __expf(mx - mn) + __expf(v - mn);
        mx = mn;
    }
    pm[r][col] = mx; ps[r][col] = sm;
    __syncthreads();
    if (tid < 32) {
        float mx2 = NEG_BIG, sm2 = 0.f;
        #pragma unroll
        for (int w = 0; w < 8; ++w) {
            const float m2 = pm[w][tid], s2 = ps[w][tid];
            const float mn = fmaxf(mx2, m2);
            sm2 = sm2 * __expf(mx2 - mn) + s2 * __expf(m2 - mn);
            mx2 = mn;
        }
        Mp2[((long)b * 128 + ti) * N + tj * 32 + tid] = mx2;
        Sp2[((long)b * 128 + ti) * N + tj * 32 + tid] = sm2;
    }
    if (ti != tj) {
        __syncthreads();
        float mxb = NEG_BIG, smb = 0.f;
        #pragma unroll
        for (int i = 0; i < 4; ++i) {
            const float v = vb[i];
            const float mn = fmaxf(mxb, v);
            smb = smb * __expf(mxb - mn) + __expf(v - mn);
            mxb = mn;
        }
        pm[r][col] = mxb; ps[r][col] = smb;
        __syncthreads();
        if (tid < 32) {
            float mx2 = NEG_BIG, sm2 = 0.f;
            #pragma unroll
            for (int w = 0; w < 8; ++w) {
                const float m2 = pm[w][tid], s2 = ps[w][tid];
                const float mn = fmaxf(mx2, m2);
                sm2 = sm2 * __expf(mx2 - mn) + s2 * __expf(m2 - mn);
                mx2 = mn;
            }
            Mp2[((long)b * 128 + tj) * N + ti * 32 + tid] = mx2;
            Sp2[((long)b * 128 + tj) * N + ti * 32 + tid] = sm2;
        }
    }
}

// ---------------------------------------------------------------------------
// Fused: att3 = 2*exp(att2 - M2[m])/S2[m], then 3x3 conv + BN + ReLU.
// grid: (64 x-tiles * 1024 y-tiles, B), block 256 (64x4 tile, 6x66 halo).
__global__ LB void attmap_conv(const float* __restrict__ att2,
                               const float* __restrict__ M2, const float* __restrict__ S2,
                               const float* __restrict__ w, const float* __restrict__ g,
                               float* __restrict__ out, int N)
{
    __shared__ float t[6][67];
    const int tid = threadIdx.x;
    const int tx = tid & 63, ty = tid >> 6;
    const int x0 = (blockIdx.x & 63) * 64;
    const int y0 = (blockIdx.x >> 6) * 4;
    const int b = blockIdx.y;
    const float* ap = att2 + (long)b * N * N;
    const float* m2p = M2 + (long)b * N;
    const float* s2p = S2 + (long)b * N;
    for (int e = tid; e < 396; e += 256) {
        const int hy = e / 66, hx = e % 66;
        const int yy = y0 + hy - 1, xx = x0 + hx - 1;
        float v = 0.f;
        if ((unsigned)yy < (unsigned)N && (unsigned)xx < (unsigned)N)
            v = 2.f * __expf(ap[(long)yy * N + xx] - m2p[xx]) *
                __builtin_amdgcn_rcpf(s2p[xx]);
        t[hy][hx] = v;
    }
    __syncthreads();
    float acc = 0.f;
    #pragma unroll
    for (int k = 0; k < 9; ++k)
        acc = fmaf(w[k], t[ty + k / 3][tx + k % 3], acc);
    const float scale = g[0] * BN_SCALE, beta = g[1];
    out[(long)b * N * N + (long)(y0 + ty) * N + x0 + tx] =
        fmaxf(fmaf(acc, scale, beta), 0.f);
}

// ===========================================================================
extern "C" void kernel_launch(void* const* d_in, const int* in_sizes, int n_in,
                              void* d_out, int out_size, void* d_ws, size_t ws_size,
                              hipStream_t stream)
{
    const float* xs   = (const float*)d_in[0];
    const float* xc   = (const float*)d_in[1];
    const float* w_g1 = (const float*)d_in[2];
    const float* g_g1 = (const float*)d_in[3];
    const float* w_g2 = (const float*)d_in[4];
    const float* g_g2 = (const float*)d_in[5];
    const float* w_ls = (const float*)d_in[6];
    const float* b_ls = (const float*)d_in[7];
    const float* g_ls = (const float*)d_in[8];
    const float* w_lc = (const float*)d_in[9];
    const float* b_lc = (const float*)d_in[10];
    const float* g_lc = (const float*)d_in[11];
    const float* w_c1 = (const float*)d_in[12];
    const float* g_c1 = (const float*)d_in[13];
    const float* w_c2 = (const float*)d_in[14];
    const float* g_c2 = (const float*)d_in[15];
    const float* w_o1 = (const float*)d_in[16];
    const float* g_o1 = (const float*)d_in[17];
    const float* w_o2 = (const float*)d_in[18];
    const float* g_o2 = (const float*)d_in[19];
    const float* w_oa = (const float*)d_in[20];
    const float* g_oa = (const float*)d_in[21];

    const int B = 2, HW = 4096, N = 4096;

    // ---- workspace layout (float offsets) ----
    float* ws = (float*)d_ws;
    float* xs1    = ws;                       // 524288
    float* xc1    = ws + 524288;              // 1048576
    float* xs1T   = ws + 1572864;             // 524288 (reuses fs/fc slots)
    float* fs     = ws + 1572864;             // 262144 (dead after att_gemm)
    float* fc     = ws + 1835008;             // 262144
    float* t32    = ws + 2097152;             // 262144
    float* outs_w = ws + 2359296;             // 524288
    float* outc_w = ws + 2883584;             // 1048576 (first holds xc1T)
    float* xc1T   = ws + 2883584;
    float* gs_w   = ws + 3932160;             // 64
    float* gc_w   = ws + 3932224;             // 64
    float* Mc     = ws + 3932288;             // 8192
    float* Sc     = ws + 3940480;             // 8192
    float* Mr     = ws + 3948672;             // 8192
    float* Sr     = ws + 3956864;             // 8192
    float* M2     = ws + 3965056;             // 8192
    float* S2     = ws + 3973248;             // 8192
    float* Mp     = ws + 3981440;             // 131072
    float* Sp     = ws + 4112512;             // 131072
    float* att    = ws + 4243584;             // 33554432

    // ---- d_out layout ----
    float* out = (float*)d_out;
    float* out_attmap = out;                       // 33554432 (scratch until end)
    float* out_s      = out + 33554432;            // 524288
    float* out_c      = out + 34078720;            // 1048576
    float* out_gs     = out + 35127296;            // 64
    float* out_gc     = out + 35127360;            // 64
    float* Mp2        = out;                       // 1048576 (after outc partials die)
    float* Sp2        = out + 1048576;             // 1048576

    const dim3 blk(256);

    // global context
    conv3x3_t16<<<dim3(16, 4, B), blk, 0, stream>>>(xs, nullptr, w_g1, nullptr, g_g1, nullptr, t32, 0, 64, 32);
    gap_kernel<<<dim3(32, B), blk, 0, stream>>>(t32, gs_w, out_gs, 32, HW);
    conv3x3_t16<<<dim3(16, 4, B), blk, 0, stream>>>(xc, nullptr, w_g2, nullptr, g_g2, nullptr, t32, 0, 128, 32);
    gap_kernel<<<dim3(32, B), blk, 0, stream>>>(t32, gc_w, out_gc, 32, HW);
    // local fusion convs + residual
    conv3x3_t16<<<dim3(16, 8, B), blk, 0, stream>>>(xs, gs_w, w_ls, b_ls, g_ls, xs, xs1, 32, 64, 64);
    conv3x3_t16<<<dim3(16, 16, B), blk, 0, stream>>>(xc, gc_w, w_lc, b_lc, g_lc, xc, xc1, 32, 128, 128);
    // attention features
    conv3x3_t16<<<dim3(16, 4, B), blk, 0, stream>>>(xs1, nullptr, w_c1, nullptr, g_c1, nullptr, fs, 0, 64, 32);
    conv3x3_t16<<<dim3(16, 4, B), blk, 0, stream>>>(xc1, nullptr, w_c2, nullptr, g_c2, nullptr, fc, 0, 128, 32);
    // att = fs^T fc
    att_gemm<<<dim3(16, 256, B), blk, 0, stream>>>(fs, fc, att, N);
    // transposes (fs/fc dead now)
    transpose_cn<<<dim3(128, 2, B), blk, 0, stream>>>(xs1, xs1T, 64, N);
    transpose_cn<<<dim3(128, 4, B), blk, 0, stream>>>(xc1, xc1T, 128, N);
    // column stats of att
    colstats_part<<<dim3(16, 16, B), blk, 0, stream>>>(att, Mp, Sp, N, 16);
    colstats_comb<<<dim3(16, B), blk, 0, stream>>>(Mp, Sp, Mc, Sc, N, 16);
    // row stats of att
    rowstats<<<dim3(N, B), blk, 0, stream>>>(att, Mr, Sr, N);
    // outs = xs1 @ colsoftmax(att)
    outs_part2<<<dim3(16, 32, B), blk, 0, stream>>>(att, xs1T, Mc, out_attmap, N, 32);
    outs_reduce<<<dim3((B * 64 * N) / 256), blk, 0, stream>>>(out_attmap, Sc, outs_w, N, 32);
    // outc = xc1 @ rowsoftmax(att)^T (exp fused, partials reuse d_out scratch)
    outc_part<<<dim3(64, 8, B), blk, 0, stream>>>(att, xc1T, Mr, out_attmap, N, 8);
    outc_reduce<<<dim3((B * 128 * N) / 256), blk, 0, stream>>>(out_attmap, Sr, outc_w, N, 8);
    // att2 = att + att^T in place, with fused column partial stats
    att2_sym_stats<<<dim3(N / 32, N / 32, B), blk, 0, stream>>>(att, Mp2, Sp2, N);
    colstats_comb<<<dim3(16, B), blk, 0, stream>>>(Mp2, Sp2, M2, S2, N, 128);
    // fused att3 + 3x3 conv + BN + ReLU
    attmap_conv<<<dim3(64 * 1024, B), blk, 0, stream>>>(att, M2, S2, w_oa, g_oa, out_attmap, N);
    // output convs + residuals
    conv3x3_t16<<<dim3(16, 8, B), blk, 0, stream>>>(outs_w, nullptr, w_o1, nullptr, g_o1, xs1, out_s, 0, 64, 64);
    conv3x3_t16<<<dim3(16, 16, B), blk, 0, stream>>>(outc_w, nullptr, w_o2, nullptr, g_o2, xc1, out_c, 0, 128, 128);
}

// Round 4
// 1620.338 us; speedup vs baseline: 1.6084x; 1.3597x over previous
//
#include <hip/hip_runtime.h>

// AGLI_5703716569604 — round 3: tiled-GEMM softmax-apply stages.
// B=2, ch1=64, ch2=128, H=W=64, N=4096, att [B,4096,4096].

#define LB __launch_bounds__(256)

constexpr float BN_SCALE = 0.99999500003749968f; // 1/sqrt(1+1e-5)
constexpr float NEG_BIG  = -3.402823466e38f;

// ---------------------------------------------------------------------------
// Tiled 3x3 conv (pad=1) for H=W=64 stages.
__global__ LB void conv3x3_t16(
    const float* __restrict__ in, const float* __restrict__ gconst,
    const float* __restrict__ w, const float* __restrict__ bias,
    const float* __restrict__ bn, const float* __restrict__ residual,
    float* __restrict__ out, int Cg, int Cin, int Cout)
{
    constexpr int OCT = 8;
    const int tid = threadIdx.x;
    const int tx = tid & 15, ty = tid >> 4;
    const int x0 = (blockIdx.x & 3) * 16, y0 = (blockIdx.x >> 2) * 16;
    const int oc0 = blockIdx.y * OCT;
    const int b = blockIdx.z;
    const int HW = 4096;
    const int Ct = Cg + Cin;

    __shared__ float tile[18][19];
    __shared__ float wg[OCT][10];

    if (Cg > 0) {
        for (int e = tid; e < OCT * 9; e += 256) {
            const int oc = e / 9, k = e % 9;
            const float* wq = w + ((long)(oc0 + oc) * Ct) * 9 + k;
            float s = 0.f;
            for (int ic = 0; ic < Cg; ++ic) s += gconst[b * Cg + ic] * wq[ic * 9];
            wg[oc][k] = s;
        }
        __syncthreads();
    }

    float acc[OCT];
    #pragma unroll
    for (int oc = 0; oc < OCT; ++oc) acc[oc] = bias ? bias[oc0 + oc] : 0.f;

    const int x = x0 + tx, y = y0 + ty;
    if (Cg > 0) {
        #pragma unroll
        for (int k = 0; k < 9; ++k) {
            const int dy = k / 3, dx = k % 3;
            if ((unsigned)(y + dy - 1) < 64u && (unsigned)(x + dx - 1) < 64u) {
                #pragma unroll
                for (int oc = 0; oc < OCT; ++oc) acc[oc] += wg[oc][k];
            }
        }
    }

    const float* ib = in + (long)b * Cin * HW;
    for (int ic = 0; ic < Cin; ++ic) {
        __syncthreads();
        #pragma unroll
        for (int r = 0; r < 2; ++r) {
            const int e = tid + r * 256;
            if (e < 324) {
                const int hy = e / 18, hx = e % 18;
                const int yy = y0 + hy - 1, xx = x0 + hx - 1;
                float v = 0.f;
                if ((unsigned)yy < 64u && (unsigned)xx < 64u)
                    v = ib[(long)ic * HW + yy * 64 + xx];
                tile[hy][hx] = v;
            }
        }
        __syncthreads();
        float p[9];
        #pragma unroll
        for (int k = 0; k < 9; ++k) p[k] = tile[ty + k / 3][tx + k % 3];
        const float* wq = w + ((long)oc0 * Ct + (Cg + ic)) * 9;
        #pragma unroll
        for (int oc = 0; oc < OCT; ++oc) {
            #pragma unroll
            for (int k = 0; k < 9; ++k)
                acc[oc] = fmaf(p[k], wq[(long)oc * Ct * 9 + k], acc[oc]);
        }
    }

    const long obase = ((long)b * Cout + oc0) * HW + y * 64 + x;
    #pragma unroll
    for (int oc = 0; oc < OCT; ++oc) {
        const float scale = bn[oc0 + oc] * BN_SCALE;
        const float beta  = bn[Cout + oc0 + oc];
        float v = fmaxf(fmaf(acc[oc], scale, beta), 0.0f);
        const long oidx = obase + (long)oc * HW;
        if (residual) v += residual[oidx];
        out[oidx] = v;
    }
}

// ---------------------------------------------------------------------------
__global__ LB void gap_kernel(const float* __restrict__ in,
                              float* __restrict__ o1, float* __restrict__ o2,
                              int C, int HW)
{
    const int c = blockIdx.x, b = blockIdx.y;
    const float* p = in + ((long)b * C + c) * HW;
    float s = 0.f;
    for (int i = threadIdx.x; i < HW; i += 256) s += p[i];
    #pragma unroll
    for (int off = 32; off; off >>= 1) s += __shfl_down(s, off);
    __shared__ float red[4];
    if ((threadIdx.x & 63) == 0) red[threadIdx.x >> 6] = s;
    __syncthreads();
    if (threadIdx.x == 0) {
        const float t = (red[0] + red[1] + red[2] + red[3]) / (float)HW;
        o1[b * C + c] = t;
        o2[b * C + c] = t;
    }
}

// ---------------------------------------------------------------------------
// att[b,n,m] = sum_c fs[b,c,n] * fc[b,c,m], C=32.
__global__ LB void att_gemm(const float* __restrict__ fs, const float* __restrict__ fc,
                            float* __restrict__ att, int N)
{
    __shared__ float lfs[32][17];
    const int tid = threadIdx.x;
    const int m  = blockIdx.x * 256 + tid;
    const int n0 = blockIdx.y * 16;
    const int b  = blockIdx.z;
    for (int i = tid; i < 32 * 16; i += 256) {
        const int c = i >> 4, nn = i & 15;
        lfs[c][nn] = fs[((long)b * 32 + c) * N + n0 + nn];
    }
    __syncthreads();
    float acc[16];
    #pragma unroll
    for (int i = 0; i < 16; ++i) acc[i] = 0.f;
    const float* fcp = fc + (long)b * 32 * N + m;
    #pragma unroll
    for (int c = 0; c < 32; ++c) {
        const float f = fcp[(long)c * N];
        #pragma unroll
        for (int nn = 0; nn < 16; ++nn) acc[nn] = fmaf(lfs[c][nn], f, acc[nn]);
    }
    float* op = att + ((long)b * N + n0) * N + m;
    #pragma unroll
    for (int nn = 0; nn < 16; ++nn) op[(long)nn * N] = acc[nn];
}

// ---------------------------------------------------------------------------
// Column-wise online (max, sum-exp) over an n-chunk. grid: (N/256, S, B)
__global__ LB void colstats_part(const float* __restrict__ att,
                                 float* __restrict__ Mp, float* __restrict__ Sp,
                                 int N, int S)
{
    const int m = blockIdx.x * 256 + threadIdx.x;
    const int s = blockIdx.y, b = blockIdx.z;
    const int chunk = N / S;
    const float* p = att + (long)b * N * N + (long)s * chunk * N + m;
    float mx = NEG_BIG, sum = 0.f;
    for (int n = 0; n < chunk; ++n) {
        const float v = p[(long)n * N];
        if (v > mx) { sum = sum * __expf(mx - v) + 1.f; mx = v; }
        else        { sum += __expf(v - mx); }
    }
    Mp[((long)b * S + s) * N + m] = mx;
    Sp[((long)b * S + s) * N + m] = sum;
}

// grid: (N/256, B); combines S partial (max,sumexp) sets.
__global__ LB void colstats_comb(const float* __restrict__ Mp, const float* __restrict__ Sp,
                                 float* __restrict__ M, float* __restrict__ Sm,
                                 int N, int S)
{
    const int m = blockIdx.x * 256 + threadIdx.x;
    const int b = blockIdx.y;
    float mx = NEG_BIG, sum = 0.f;
    for (int s = 0; s < S; ++s) {
        const float m2 = Mp[((long)b * S + s) * N + m];
        const float s2 = Sp[((long)b * S + s) * N + m];
        const float mn = fmaxf(mx, m2);
        sum = sum * __expf(mx - mn) + s2 * __expf(m2 - mn);
        mx = mn;
    }
    M[(long)b * N + m]  = mx;
    Sm[(long)b * N + m] = sum;
}

// ---------------------------------------------------------------------------
// Row-wise (max, sum-exp). grid: (N, B), block 256
__global__ LB void rowstats(const float* __restrict__ att,
                            float* __restrict__ Mr, float* __restrict__ Sr, int N)
{
    const int n = blockIdx.x, b = blockIdx.y;
    const float* p = att + ((long)b * N + n) * N;
    float mx = NEG_BIG, sum = 0.f;
    for (int m = threadIdx.x; m < N; m += 256) {
        const float v = p[m];
        if (v > mx) { sum = sum * __expf(mx - v) + 1.f; mx = v; }
        else        { sum += __expf(v - mx); }
    }
    #pragma unroll
    for (int off = 32; off; off >>= 1) {
        const float m2 = __shfl_down(mx, off);
        const float s2 = __shfl_down(sum, off);
        const float mn = fmaxf(mx, m2);
        sum = sum * __expf(mx - mn) + s2 * __expf(m2 - mn);
        mx = mn;
    }
    __shared__ float rm[4], rs[4];
    const int lane = threadIdx.x & 63, wv = threadIdx.x >> 6;
    if (lane == 0) { rm[wv] = mx; rs[wv] = sum; }
    __syncthreads();
    if (threadIdx.x == 0) {
        mx = rm[0]; sum = rs[0];
        for (int w = 1; w < 4; ++w) {
            const float mn = fmaxf(mx, rm[w]);
            sum = sum * __expf(mx - mn) + rs[w] * __expf(rm[w] - mn);
            mx = mn;
        }
        Mr[(long)b * N + n] = mx;
        Sr[(long)b * N + n] = sum;
    }
}

// ---------------------------------------------------------------------------
// Softmax-apply GEMM with K-split.
// part[b,s,row,col] = sum_{k in chunk s} X[b,row,k] * exp(attv - Mv[b,col])
//   MODE 0 (outs): attv = att[b, k, col]   (col-softmax, Mv = Mc)
//   MODE 1 (outc): attv = att[b, col, k]   (row-softmax, Mv = Mr)
// grid: (N/128, S, B), block 256. Tile MROWS x 128, K-chunk 32.
template<int MROWS, int MODE>
__global__ LB void sm_gemm(const float* __restrict__ X,
                           const float* __restrict__ att,
                           const float* __restrict__ Mv,
                           float* __restrict__ part, int N, int S)
{
    constexpr int R = (MROWS == 128) ? 8 : 4;  // rows per thread
    __shared__ float ldsA[32][MROWS + 4];
    __shared__ float ldsB[32][132];
    __shared__ float mcol[128];

    const int tid = threadIdx.x;
    const int col0 = blockIdx.x * 128;
    const int s = blockIdx.y, b = blockIdx.z;
    const int chunk = N / S;

    if (tid < 128) mcol[tid] = Mv[(long)b * N + col0 + tid];

    float acc[R][8];
    #pragma unroll
    for (int i = 0; i < R; ++i)
        #pragma unroll
        for (int j = 0; j < 8; ++j) acc[i][j] = 0.f;

    const float* Xb = X + (long)b * MROWS * N;
    const float* ab = att + (long)b * N * N;

    // staging index precompute
    constexpr int TPR = 256 / MROWS;       // threads per X row
    const int ac = tid / TPR;              // X row (channel)
    const int aq = tid % TPR;              // which f4 group
    const int ty = tid >> 4, txl = tid & 15;

    for (int k0 = s * chunk; k0 < (s + 1) * chunk; k0 += 32) {
        __syncthreads();
        // stage A: ldsA[kk][c] = X[c][k0+kk]
        #pragma unroll
        for (int jj = 0; jj < 8 / TPR; ++jj) {
            const int f = aq * (8 / TPR) + jj;
            const float4 v = *(const float4*)&Xb[(long)ac * N + k0 + f * 4];
            ldsA[f * 4 + 0][ac] = v.x;
            ldsA[f * 4 + 1][ac] = v.y;
            ldsA[f * 4 + 2][ac] = v.z;
            ldsA[f * 4 + 3][ac] = v.w;
        }
        // stage B with fused exp
        if (MODE == 0) {
            const int kk = tid >> 3, q = tid & 7;
            #pragma unroll
            for (int jj = 0; jj < 4; ++jj) {
                const int f = q * 4 + jj;
                const float4 v = *(const float4*)&ab[(long)(k0 + kk) * N + col0 + f * 4];
                ldsB[kk][f * 4 + 0] = __expf(v.x - mcol[f * 4 + 0]);
                ldsB[kk][f * 4 + 1] = __expf(v.y - mcol[f * 4 + 1]);
                ldsB[kk][f * 4 + 2] = __expf(v.z - mcol[f * 4 + 2]);
                ldsB[kk][f * 4 + 3] = __expf(v.w - mcol[f * 4 + 3]);
            }
        } else {
            const int cc = tid >> 1, q = tid & 1;
            const float mv = mcol[cc];
            #pragma unroll
            for (int jj = 0; jj < 4; ++jj) {
                const int f = q * 4 + jj;
                const float4 v = *(const float4*)&ab[(long)(col0 + cc) * N + k0 + f * 4];
                ldsB[f * 4 + 0][cc] = __expf(v.x - mv);
                ldsB[f * 4 + 1][cc] = __expf(v.y - mv);
                ldsB[f * 4 + 2][cc] = __expf(v.z - mv);
                ldsB[f * 4 + 3][cc] = __expf(v.w - mv);
            }
        }
        __syncthreads();
        // compute
        #pragma unroll
        for (int kk = 0; kk < 32; ++kk) {
            float a[R], bb[8];
            #pragma unroll
            for (int i = 0; i < R; i += 4)
                *(float4*)&a[i] = *(const float4*)&ldsA[kk][ty * R + i];
            *(float4*)&bb[0] = *(const float4*)&ldsB[kk][txl * 8];
            *(float4*)&bb[4] = *(const float4*)&ldsB[kk][txl * 8 + 4];
            #pragma unroll
            for (int i = 0; i < R; ++i)
                #pragma unroll
                for (int j = 0; j < 8; ++j)
                    acc[i][j] = fmaf(a[i], bb[j], acc[i][j]);
        }
    }

    float* pp = part + ((long)(b * S + s) * MROWS) * N + col0;
    #pragma unroll
    for (int i = 0; i < R; ++i) {
        float* row = pp + (long)(ty * R + i) * N + txl * 8;
        *(float4*)&row[0] = make_float4(acc[i][0], acc[i][1], acc[i][2], acc[i][3]);
        *(float4*)&row[4] = make_float4(acc[i][4], acc[i][5], acc[i][6], acc[i][7]);
    }
}

// Sum K-split partials and divide by per-column softmax denom.
// grid: (B*C*N/256). part: [B,S,C,N], denom: [B,N].
template<int C>
__global__ LB void sm_reduce(const float* __restrict__ part, const float* __restrict__ denom,
                             float* __restrict__ outp, int N, int S)
{
    const long idx = (long)blockIdx.x * 256 + threadIdx.x;
    const int m = (int)(idx & (long)(N - 1));
    const long bc = idx >> 12;
    const int c = (int)(bc & (C - 1));
    const int b = (int)(bc / C);
    float s = 0.f;
    for (int ss = 0; ss < S; ++ss)
        s += part[((long)(b * S + ss) * C + c) * N + m];
    outp[idx] = s / denom[(long)b * N + m];
}

// ---------------------------------------------------------------------------
// In-place att += att^T AND per-tile-row column stats of the result.
// grid: (N/32, N/32, B); ti<=tj do work. Mp2/Sp2: [B,128,N].
__global__ LB void att2_sym_stats(float* __restrict__ att,
                                  float* __restrict__ Mp2, float* __restrict__ Sp2, int N)
{
    const int ti = blockIdx.x, tj = blockIdx.y;
    if (ti > tj) return;
    const int b = blockIdx.z;
    __shared__ float Ta[32][33], Tb[32][33];
    __shared__ float pm[8][33], ps[8][33];
    const long base = (long)b * N * N;
    const int tid = threadIdx.x;
    const int r = tid >> 5, col = tid & 31;
    #pragma unroll
    for (int i = 0; i < 4; ++i) {
        const int rr = r + i * 8;
        Ta[rr][col] = att[base + (long)(ti * 32 + rr) * N + tj * 32 + col];
        Tb[rr][col] = att[base + (long)(tj * 32 + rr) * N + ti * 32 + col];
    }
    __syncthreads();
    float va[4], vb[4];
    #pragma unroll
    for (int i = 0; i < 4; ++i) {
        const int rr = r + i * 8;
        va[i] = Ta[rr][col] + Tb[col][rr];
        att[base + (long)(ti * 32 + rr) * N + tj * 32 + col] = va[i];
        if (ti != tj) {
            vb[i] = Tb[rr][col] + Ta[col][rr];
            att[base + (long)(tj * 32 + rr) * N + ti * 32 + col] = vb[i];
        }
    }
    float mx = NEG_BIG, sm = 0.f;
    #pragma unroll
    for (int i = 0; i < 4; ++i) {
        const float v = va[i];
        const float mn = fmaxf(mx, v);
        sm = sm * __expf(mx - mn) + __expf(v - mn);
        mx = mn;
    }
    pm[r][col] = mx; ps[r][col] = sm;
    __syncthreads();
    if (tid < 32) {
        float mx2 = NEG_BIG, sm2 = 0.f;
        #pragma unroll
        for (int w = 0; w < 8; ++w) {
            const float m2 = pm[w][tid], s2 = ps[w][tid];
            const float mn = fmaxf(mx2, m2);
            sm2 = sm2 * __expf(mx2 - mn) + s2 * __expf(m2 - mn);
            mx2 = mn;
        }
        Mp2[((long)b * 128 + ti) * N + tj * 32 + tid] = mx2;
        Sp2[((long)b * 128 + ti) * N + tj * 32 + tid] = sm2;
    }
    if (ti != tj) {
        __syncthreads();
        float mxb = NEG_BIG, smb = 0.f;
        #pragma unroll
        for (int i = 0; i < 4; ++i) {
            const float v = vb[i];
            const float mn = fmaxf(mxb, v);
            smb = smb * __expf(mxb - mn) + __expf(v - mn);
            mxb = mn;
        }
        pm[r][col] = mxb; ps[r][col] = smb;
        __syncthreads();
        if (tid < 32) {
            float mx2 = NEG_BIG, sm2 = 0.f;
            #pragma unroll
            for (int w = 0; w < 8; ++w) {
                const float m2 = pm[w][tid], s2 = ps[w][tid];
                const float mn = fmaxf(mx2, m2);
                sm2 = sm2 * __expf(mx2 - mn) + s2 * __expf(m2 - mn);
                mx2 = mn;
            }
            Mp2[((long)b * 128 + tj) * N + ti * 32 + tid] = mx2;
            Sp2[((long)b * 128 + tj) * N + ti * 32 + tid] = sm2;
        }
    }
}

// ---------------------------------------------------------------------------
// Fused: att3 = 2*exp(att2 - M2[m])/S2[m], then 3x3 conv + BN + ReLU.
__global__ LB void attmap_conv(const float* __restrict__ att2,
                               const float* __restrict__ M2, const float* __restrict__ S2,
                               const float* __restrict__ w, const float* __restrict__ g,
                               float* __restrict__ out, int N)
{
    __shared__ float t[6][67];
    const int tid = threadIdx.x;
    const int tx = tid & 63, ty = tid >> 6;
    const int x0 = (blockIdx.x & 63) * 64;
    const int y0 = (blockIdx.x >> 6) * 4;
    const int b = blockIdx.y;
    const float* ap = att2 + (long)b * N * N;
    const float* m2p = M2 + (long)b * N;
    const float* s2p = S2 + (long)b * N;
    for (int e = tid; e < 396; e += 256) {
        const int hy = e / 66, hx = e % 66;
        const int yy = y0 + hy - 1, xx = x0 + hx - 1;
        float v = 0.f;
        if ((unsigned)yy < (unsigned)N && (unsigned)xx < (unsigned)N)
            v = 2.f * __expf(ap[(long)yy * N + xx] - m2p[xx]) *
                __builtin_amdgcn_rcpf(s2p[xx]);
        t[hy][hx] = v;
    }
    __syncthreads();
    float acc = 0.f;
    #pragma unroll
    for (int k = 0; k < 9; ++k)
        acc = fmaf(w[k], t[ty + k / 3][tx + k % 3], acc);
    const float scale = g[0] * BN_SCALE, beta = g[1];
    out[(long)b * N * N + (long)(y0 + ty) * N + x0 + tx] =
        fmaxf(fmaf(acc, scale, beta), 0.f);
}

// ===========================================================================
extern "C" void kernel_launch(void* const* d_in, const int* in_sizes, int n_in,
                              void* d_out, int out_size, void* d_ws, size_t ws_size,
                              hipStream_t stream)
{
    const float* xs   = (const float*)d_in[0];
    const float* xc   = (const float*)d_in[1];
    const float* w_g1 = (const float*)d_in[2];
    const float* g_g1 = (const float*)d_in[3];
    const float* w_g2 = (const float*)d_in[4];
    const float* g_g2 = (const float*)d_in[5];
    const float* w_ls = (const float*)d_in[6];
    const float* b_ls = (const float*)d_in[7];
    const float* g_ls = (const float*)d_in[8];
    const float* w_lc = (const float*)d_in[9];
    const float* b_lc = (const float*)d_in[10];
    const float* g_lc = (const float*)d_in[11];
    const float* w_c1 = (const float*)d_in[12];
    const float* g_c1 = (const float*)d_in[13];
    const float* w_c2 = (const float*)d_in[14];
    const float* g_c2 = (const float*)d_in[15];
    const float* w_o1 = (const float*)d_in[16];
    const float* g_o1 = (const float*)d_in[17];
    const float* w_o2 = (const float*)d_in[18];
    const float* g_o2 = (const float*)d_in[19];
    const float* w_oa = (const float*)d_in[20];
    const float* g_oa = (const float*)d_in[21];

    const int B = 2, HW = 4096, N = 4096;

    // ---- workspace layout (float offsets) ----
    float* ws = (float*)d_ws;
    float* xs1    = ws;                       // 524288
    float* xc1    = ws + 524288;              // 1048576
    float* fs     = ws + 1572864;             // 262144
    float* fc     = ws + 1835008;             // 262144
    float* t32    = ws + 2097152;             // 262144
    float* outs_w = ws + 2359296;             // 524288
    float* outc_w = ws + 2883584;             // 1048576
    float* gs_w   = ws + 3932160;             // 64
    float* gc_w   = ws + 3932224;             // 64
    float* Mc     = ws + 3932288;             // 8192
    float* Sc     = ws + 3940480;             // 8192
    float* Mr     = ws + 3948672;             // 8192
    float* Sr     = ws + 3956864;             // 8192
    float* M2     = ws + 3965056;             // 8192
    float* S2     = ws + 3973248;             // 8192
    float* Mp     = ws + 3981440;             // 131072
    float* Sp     = ws + 4112512;             // 131072
    float* att    = ws + 4243584;             // 33554432

    // ---- d_out layout ----
    float* out = (float*)d_out;
    float* out_attmap = out;                       // 33554432 (scratch until end)
    float* out_s      = out + 33554432;            // 524288
    float* out_c      = out + 34078720;            // 1048576
    float* out_gs     = out + 35127296;            // 64
    float* out_gc     = out + 35127360;            // 64
    float* Mp2        = out;                       // [B,128,N] (after GEMM partials die)
    float* Sp2        = out + 1048576;

    const dim3 blk(256);

    // global context
    conv3x3_t16<<<dim3(16, 4, B), blk, 0, stream>>>(xs, nullptr, w_g1, nullptr, g_g1, nullptr, t32, 0, 64, 32);
    gap_kernel<<<dim3(32, B), blk, 0, stream>>>(t32, gs_w, out_gs, 32, HW);
    conv3x3_t16<<<dim3(16, 4, B), blk, 0, stream>>>(xc, nullptr, w_g2, nullptr, g_g2, nullptr, t32, 0, 128, 32);
    gap_kernel<<<dim3(32, B), blk, 0, stream>>>(t32, gc_w, out_gc, 32, HW);
    // local fusion convs + residual
    conv3x3_t16<<<dim3(16, 8, B), blk, 0, stream>>>(xs, gs_w, w_ls, b_ls, g_ls, xs, xs1, 32, 64, 64);
    conv3x3_t16<<<dim3(16, 16, B), blk, 0, stream>>>(xc, gc_w, w_lc, b_lc, g_lc, xc, xc1, 32, 128, 128);
    // attention features
    conv3x3_t16<<<dim3(16, 4, B), blk, 0, stream>>>(xs1, nullptr, w_c1, nullptr, g_c1, nullptr, fs, 0, 64, 32);
    conv3x3_t16<<<dim3(16, 4, B), blk, 0, stream>>>(xc1, nullptr, w_c2, nullptr, g_c2, nullptr, fc, 0, 128, 32);
    // att = fs^T fc
    att_gemm<<<dim3(16, 256, B), blk, 0, stream>>>(fs, fc, att, N);
    // column stats of att
    colstats_part<<<dim3(16, 16, B), blk, 0, stream>>>(att, Mp, Sp, N, 16);
    colstats_comb<<<dim3(16, B), blk, 0, stream>>>(Mp, Sp, Mc, Sc, N, 16);
    // row stats of att
    rowstats<<<dim3(N, B), blk, 0, stream>>>(att, Mr, Sr, N);
    // outs = xs1 @ colsoftmax(att): tiled GEMM, partials in d_out scratch
    sm_gemm<64, 0><<<dim3(32, 8, B), blk, 0, stream>>>(xs1, att, Mc, out_attmap, N, 8);
    sm_reduce<64><<<dim3((B * 64 * N) / 256), blk, 0, stream>>>(out_attmap, Sc, outs_w, N, 8);
    // outc = xc1 @ rowsoftmax(att)^T: tiled GEMM
    sm_gemm<128, 1><<<dim3(32, 8, B), blk, 0, stream>>>(xc1, att, Mr, out_attmap, N, 8);
    sm_reduce<128><<<dim3((B * 128 * N) / 256), blk, 0, stream>>>(out_attmap, Sr, outc_w, N, 8);
    // att2 = att + att^T in place, with fused column partial stats
    att2_sym_stats<<<dim3(N / 32, N / 32, B), blk, 0, stream>>>(att, Mp2, Sp2, N);
    colstats_comb<<<dim3(16, B), blk, 0, stream>>>(Mp2, Sp2, M2, S2, N, 128);
    // fused att3 + 3x3 conv + BN + ReLU
    attmap_conv<<<dim3(64 * 1024, B), blk, 0, stream>>>(att, M2, S2, w_oa, g_oa, out_attmap, N);
    // output convs + residuals
    conv3x3_t16<<<dim3(16, 8, B), blk, 0, stream>>>(outs_w, nullptr, w_o1, nullptr, g_o1, xs1, out_s, 0, 64, 64);
    conv3x3_t16<<<dim3(16, 16, B), blk, 0, stream>>>(outc_w, nullptr, w_o2, nullptr, g_o2, xc1, out_c, 0, 128, 128);
}

// Round 5
// 961.117 us; speedup vs baseline: 2.7115x; 1.6859x over previous
//
#include <hip/hip_runtime.h>

// AGLI_5703716569604 — round 4: K-split double-buffered conv + combine.
// B=2, ch1=64, ch2=128, H=W=64, N=4096, att [B,4096,4096].

#define LB __launch_bounds__(256)

constexpr float BN_SCALE = 0.99999500003749968f; // 1/sqrt(1+1e-5)
constexpr float NEG_BIG  = -3.402823466e38f;

// ---------------------------------------------------------------------------
// Stage one 34x34 halo tile (stride 35) for input channel image ib.
__device__ __forceinline__ void stage_tile(const float* __restrict__ ib,
                                           float* __restrict__ buf,
                                           int x0, int y0, int tid)
{
    #pragma unroll
    for (int r = 0; r < 5; ++r) {
        const int e = tid + r * 256;
        if (e < 1156) {
            const int hy = e / 34, hx = e % 34;
            const int yy = y0 + hy - 1, xx = x0 + hx - 1;
            float v = 0.f;
            if ((unsigned)yy < 64u && (unsigned)xx < 64u)
                v = ib[yy * 64 + xx];
            buf[hy * 35 + hx] = v;
        }
    }
}

// ---------------------------------------------------------------------------
// 3x3 conv partial over an ic-chunk. Block: 256 thr = 32x32 px (2x2 per thr),
// 8 output channels, double-buffered LDS halo, one barrier per ic.
// grid: (4 tiles, Cout/8, B*ICS). part: [ICS][B][Cout][HW].
// Chunk s==0 additionally folds const-broadcast channels (gconst) + bias.
__global__ LB void conv3x3_big(
    const float* __restrict__ in,       // [B, Cin, 64, 64]
    const float* __restrict__ gconst,   // [B, Cg] or nullptr
    const float* __restrict__ w,        // [Cout, Cg+Cin, 3, 3]
    const float* __restrict__ bias,     // [Cout] or nullptr
    float* __restrict__ part,
    int Cg, int Cin, int Cout, int ICS)
{
    __shared__ float buf[2][34 * 35];
    __shared__ float wg[8][10];
    const int tid = threadIdx.x;
    const int tx = tid & 15, ty = tid >> 4;
    const int x0 = (blockIdx.x & 1) * 32, y0 = (blockIdx.x >> 1) * 32;
    const int oc0 = blockIdx.y * 8;
    const int b = blockIdx.z / ICS, s = blockIdx.z % ICS;
    const int chunk = Cin / ICS;
    const int ic0 = s * chunk;
    const int Ct = Cg + Cin;
    const int HW = 4096;

    float acc[8][4];
    #pragma unroll
    for (int oc = 0; oc < 8; ++oc)
        #pragma unroll
        for (int p = 0; p < 4; ++p) acc[oc][p] = 0.f;

    if (s == 0) {
        if (bias) {
            #pragma unroll
            for (int oc = 0; oc < 8; ++oc) {
                const float bv = bias[oc0 + oc];
                #pragma unroll
                for (int p = 0; p < 4; ++p) acc[oc][p] = bv;
            }
        }
        if (Cg > 0) {
            for (int e = tid; e < 72; e += 256) {
                const int oc = e / 9, k = e % 9;
                float sm = 0.f;
                for (int ic = 0; ic < Cg; ++ic)
                    sm += gconst[b * Cg + ic] * w[((long)(oc0 + oc) * Ct + ic) * 9 + k];
                wg[oc][k] = sm;
            }
            __syncthreads();
            #pragma unroll
            for (int k = 0; k < 9; ++k) {
                const int dy = k / 3 - 1, dx = k % 3 - 1;
                #pragma unroll
                for (int pr = 0; pr < 2; ++pr)
                    #pragma unroll
                    for (int pc = 0; pc < 2; ++pc) {
                        const int yy = y0 + ty * 2 + pr + dy;
                        const int xx = x0 + tx * 2 + pc + dx;
                        if ((unsigned)yy < 64u && (unsigned)xx < 64u) {
                            #pragma unroll
                            for (int oc = 0; oc < 8; ++oc)
                                acc[oc][pr * 2 + pc] += wg[oc][k];
                        }
                    }
            }
        }
    }

    const float* ib = in + ((long)b * Cin + ic0) * HW;
    stage_tile(ib, buf[0], x0, y0, tid);
    __syncthreads();
    int cur = 0;
    for (int i = 0; i < chunk; ++i) {
        if (i + 1 < chunk)
            stage_tile(ib + (long)(i + 1) * HW, buf[cur ^ 1], x0, y0, tid);
        float win[4][4];
        const float* bp = buf[cur] + (ty * 2) * 35 + tx * 2;
        #pragma unroll
        for (int r = 0; r < 4; ++r) {
            const float2 a = *(const float2*)&bp[r * 35];
            const float2 c = *(const float2*)&bp[r * 35 + 2];
            win[r][0] = a.x; win[r][1] = a.y; win[r][2] = c.x; win[r][3] = c.y;
        }
        const float* wq = w + ((long)oc0 * Ct + Cg + ic0 + i) * 9;
        #pragma unroll
        for (int oc = 0; oc < 8; ++oc) {
            const float* wo = wq + (long)oc * Ct * 9;
            #pragma unroll
            for (int dy = 0; dy < 3; ++dy)
                #pragma unroll
                for (int dx = 0; dx < 3; ++dx) {
                    const float wv = wo[dy * 3 + dx];
                    #pragma unroll
                    for (int pr = 0; pr < 2; ++pr)
                        #pragma unroll
                        for (int pc = 0; pc < 2; ++pc)
                            acc[oc][pr * 2 + pc] =
                                fmaf(wv, win[pr + dy][pc + dx], acc[oc][pr * 2 + pc]);
                }
        }
        __syncthreads();
        cur ^= 1;
    }

    #pragma unroll
    for (int oc = 0; oc < 8; ++oc) {
        #pragma unroll
        for (int pr = 0; pr < 2; ++pr) {
            float* q = part + (((long)s * 2 + b) * Cout + oc0 + oc) * (long)HW
                       + (y0 + ty * 2 + pr) * 64 + x0 + tx * 2;
            *(float2*)q = make_float2(acc[oc][pr * 2], acc[oc][pr * 2 + 1]);
        }
    }
}

// ---------------------------------------------------------------------------
// Sum ICS conv partials, apply BN + ReLU (+ optional residual).
// grid: (B*Cout*4096/256). out: [B,Cout,HW].
__global__ LB void conv_combine(const float* __restrict__ part,
                                const float* __restrict__ bn,
                                const float* __restrict__ residual,
                                float* __restrict__ out,
                                int Cout, int ICS)
{
    const long idx = (long)blockIdx.x * 256 + threadIdx.x;
    const int hw = (int)(idx & 4095);
    const long t = idx >> 12;
    const int c = (int)(t % Cout);
    const int b = (int)(t / Cout);
    float v = 0.f;
    for (int s = 0; s < ICS; ++s)
        v += part[(((long)s * 2 + b) * Cout + c) * 4096 + hw];
    const float scale = bn[c] * BN_SCALE, beta = bn[Cout + c];
    float r = fmaxf(fmaf(v, scale, beta), 0.f);
    if (residual) r += residual[idx];
    out[idx] = r;
}

// ---------------------------------------------------------------------------
__global__ LB void gap_kernel(const float* __restrict__ in,
                              float* __restrict__ o1, float* __restrict__ o2,
                              int C, int HW)
{
    const int c = blockIdx.x, b = blockIdx.y;
    const float* p = in + ((long)b * C + c) * HW;
    float s = 0.f;
    for (int i = threadIdx.x; i < HW; i += 256) s += p[i];
    #pragma unroll
    for (int off = 32; off; off >>= 1) s += __shfl_down(s, off);
    __shared__ float red[4];
    if ((threadIdx.x & 63) == 0) red[threadIdx.x >> 6] = s;
    __syncthreads();
    if (threadIdx.x == 0) {
        const float t = (red[0] + red[1] + red[2] + red[3]) / (float)HW;
        o1[b * C + c] = t;
        o2[b * C + c] = t;
    }
}

// ---------------------------------------------------------------------------
// att[b,n,m] = sum_c fs[b,c,n] * fc[b,c,m], C=32.
__global__ LB void att_gemm(const float* __restrict__ fs, const float* __restrict__ fc,
                            float* __restrict__ att, int N)
{
    __shared__ float lfs[32][17];
    const int tid = threadIdx.x;
    const int m  = blockIdx.x * 256 + tid;
    const int n0 = blockIdx.y * 16;
    const int b  = blockIdx.z;
    for (int i = tid; i < 32 * 16; i += 256) {
        const int c = i >> 4, nn = i & 15;
        lfs[c][nn] = fs[((long)b * 32 + c) * N + n0 + nn];
    }
    __syncthreads();
    float acc[16];
    #pragma unroll
    for (int i = 0; i < 16; ++i) acc[i] = 0.f;
    const float* fcp = fc + (long)b * 32 * N + m;
    #pragma unroll
    for (int c = 0; c < 32; ++c) {
        const float f = fcp[(long)c * N];
        #pragma unroll
        for (int nn = 0; nn < 16; ++nn) acc[nn] = fmaf(lfs[c][nn], f, acc[nn]);
    }
    float* op = att + ((long)b * N + n0) * N + m;
    #pragma unroll
    for (int nn = 0; nn < 16; ++nn) op[(long)nn * N] = acc[nn];
}

// ---------------------------------------------------------------------------
// Column-wise online (max, sum-exp) over an n-chunk. grid: (N/256, S, B)
__global__ LB void colstats_part(const float* __restrict__ att,
                                 float* __restrict__ Mp, float* __restrict__ Sp,
                                 int N, int S)
{
    const int m = blockIdx.x * 256 + threadIdx.x;
    const int s = blockIdx.y, b = blockIdx.z;
    const int chunk = N / S;
    const float* p = att + (long)b * N * N + (long)s * chunk * N + m;
    float mx = NEG_BIG, sum = 0.f;
    for (int n = 0; n < chunk; ++n) {
        const float v = p[(long)n * N];
        if (v > mx) { sum = sum * __expf(mx - v) + 1.f; mx = v; }
        else        { sum += __expf(v - mx); }
    }
    Mp[((long)b * S + s) * N + m] = mx;
    Sp[((long)b * S + s) * N + m] = sum;
}

// grid: (N/256, B); combines S partial (max,sumexp) sets.
__global__ LB void colstats_comb(const float* __restrict__ Mp, const float* __restrict__ Sp,
                                 float* __restrict__ M, float* __restrict__ Sm,
                                 int N, int S)
{
    const int m = blockIdx.x * 256 + threadIdx.x;
    const int b = blockIdx.y;
    float mx = NEG_BIG, sum = 0.f;
    for (int s = 0; s < S; ++s) {
        const float m2 = Mp[((long)b * S + s) * N + m];
        const float s2 = Sp[((long)b * S + s) * N + m];
        const float mn = fmaxf(mx, m2);
        sum = sum * __expf(mx - mn) + s2 * __expf(m2 - mn);
        mx = mn;
    }
    M[(long)b * N + m]  = mx;
    Sm[(long)b * N + m] = sum;
}

// ---------------------------------------------------------------------------
// Row-wise (max, sum-exp). grid: (N, B), block 256
__global__ LB void rowstats(const float* __restrict__ att,
                            float* __restrict__ Mr, float* __restrict__ Sr, int N)
{
    const int n = blockIdx.x, b = blockIdx.y;
    const float* p = att + ((long)b * N + n) * N;
    float mx = NEG_BIG, sum = 0.f;
    for (int m = threadIdx.x; m < N; m += 256) {
        const float v = p[m];
        if (v > mx) { sum = sum * __expf(mx - v) + 1.f; mx = v; }
        else        { sum += __expf(v - mx); }
    }
    #pragma unroll
    for (int off = 32; off; off >>= 1) {
        const float m2 = __shfl_down(mx, off);
        const float s2 = __shfl_down(sum, off);
        const float mn = fmaxf(mx, m2);
        sum = sum * __expf(mx - mn) + s2 * __expf(m2 - mn);
        mx = mn;
    }
    __shared__ float rm[4], rs[4];
    const int lane = threadIdx.x & 63, wv = threadIdx.x >> 6;
    if (lane == 0) { rm[wv] = mx; rs[wv] = sum; }
    __syncthreads();
    if (threadIdx.x == 0) {
        mx = rm[0]; sum = rs[0];
        for (int w = 1; w < 4; ++w) {
            const float mn = fmaxf(mx, rm[w]);
            sum = sum * __expf(mx - mn) + rs[w] * __expf(rm[w] - mn);
            mx = mn;
        }
        Mr[(long)b * N + n] = mx;
        Sr[(long)b * N + n] = sum;
    }
}

// ---------------------------------------------------------------------------
// Softmax-apply GEMM with K-split.
// part[b,s,row,col] = sum_{k in chunk s} X[b,row,k] * exp(attv - Mv[b,col])
//   MODE 0 (outs): attv = att[b, k, col]   (col-softmax, Mv = Mc)
//   MODE 1 (outc): attv = att[b, col, k]   (row-softmax, Mv = Mr)
// grid: (N/128, S, B), block 256. Tile MROWS x 128, K-chunk 32.
template<int MROWS, int MODE>
__global__ LB void sm_gemm(const float* __restrict__ X,
                           const float* __restrict__ att,
                           const float* __restrict__ Mv,
                           float* __restrict__ part, int N, int S)
{
    constexpr int R = (MROWS == 128) ? 8 : 4;  // rows per thread
    __shared__ float ldsA[32][MROWS + 4];
    __shared__ float ldsB[32][132];
    __shared__ float mcol[128];

    const int tid = threadIdx.x;
    const int col0 = blockIdx.x * 128;
    const int s = blockIdx.y, b = blockIdx.z;
    const int chunk = N / S;

    if (tid < 128) mcol[tid] = Mv[(long)b * N + col0 + tid];

    float acc[R][8];
    #pragma unroll
    for (int i = 0; i < R; ++i)
        #pragma unroll
        for (int j = 0; j < 8; ++j) acc[i][j] = 0.f;

    const float* Xb = X + (long)b * MROWS * N;
    const float* ab = att + (long)b * N * N;

    constexpr int TPR = 256 / MROWS;
    const int ac = tid / TPR;
    const int aq = tid % TPR;
    const int ty = tid >> 4, txl = tid & 15;

    for (int k0 = s * chunk; k0 < (s + 1) * chunk; k0 += 32) {
        __syncthreads();
        #pragma unroll
        for (int jj = 0; jj < 8 / TPR; ++jj) {
            const int f = aq * (8 / TPR) + jj;
            const float4 v = *(const float4*)&Xb[(long)ac * N + k0 + f * 4];
            ldsA[f * 4 + 0][ac] = v.x;
            ldsA[f * 4 + 1][ac] = v.y;
            ldsA[f * 4 + 2][ac] = v.z;
            ldsA[f * 4 + 3][ac] = v.w;
        }
        if (MODE == 0) {
            const int kk = tid >> 3, q = tid & 7;
            #pragma unroll
            for (int jj = 0; jj < 4; ++jj) {
                const int f = q * 4 + jj;
                const float4 v = *(const float4*)&ab[(long)(k0 + kk) * N + col0 + f * 4];
                ldsB[kk][f * 4 + 0] = __expf(v.x - mcol[f * 4 + 0]);
                ldsB[kk][f * 4 + 1] = __expf(v.y - mcol[f * 4 + 1]);
                ldsB[kk][f * 4 + 2] = __expf(v.z - mcol[f * 4 + 2]);
                ldsB[kk][f * 4 + 3] = __expf(v.w - mcol[f * 4 + 3]);
            }
        } else {
            const int cc = tid >> 1, q = tid & 1;
            const float mv = mcol[cc];
            #pragma unroll
            for (int jj = 0; jj < 4; ++jj) {
                const int f = q * 4 + jj;
                const float4 v = *(const float4*)&ab[(long)(col0 + cc) * N + k0 + f * 4];
                ldsB[f * 4 + 0][cc] = __expf(v.x - mv);
                ldsB[f * 4 + 1][cc] = __expf(v.y - mv);
                ldsB[f * 4 + 2][cc] = __expf(v.z - mv);
                ldsB[f * 4 + 3][cc] = __expf(v.w - mv);
            }
        }
        __syncthreads();
        #pragma unroll
        for (int kk = 0; kk < 32; ++kk) {
            float a[R], bb[8];
            #pragma unroll
            for (int i = 0; i < R; i += 4)
                *(float4*)&a[i] = *(const float4*)&ldsA[kk][ty * R + i];
            *(float4*)&bb[0] = *(const float4*)&ldsB[kk][txl * 8];
            *(float4*)&bb[4] = *(const float4*)&ldsB[kk][txl * 8 + 4];
            #pragma unroll
            for (int i = 0; i < R; ++i)
                #pragma unroll
                for (int j = 0; j < 8; ++j)
                    acc[i][j] = fmaf(a[i], bb[j], acc[i][j]);
        }
    }

    float* pp = part + ((long)(b * S + s) * MROWS) * N + col0;
    #pragma unroll
    for (int i = 0; i < R; ++i) {
        float* row = pp + (long)(ty * R + i) * N + txl * 8;
        *(float4*)&row[0] = make_float4(acc[i][0], acc[i][1], acc[i][2], acc[i][3]);
        *(float4*)&row[4] = make_float4(acc[i][4], acc[i][5], acc[i][6], acc[i][7]);
    }
}

// Sum K-split partials and divide by per-column softmax denom.
template<int C>
__global__ LB void sm_reduce(const float* __restrict__ part, const float* __restrict__ denom,
                             float* __restrict__ outp, int N, int S)
{
    const long idx = (long)blockIdx.x * 256 + threadIdx.x;
    const int m = (int)(idx & (long)(N - 1));
    const long bc = idx >> 12;
    const int c = (int)(bc & (C - 1));
    const int b = (int)(bc / C);
    float s = 0.f;
    for (int ss = 0; ss < S; ++ss)
        s += part[((long)(b * S + ss) * C + c) * N + m];
    outp[idx] = s / denom[(long)b * N + m];
}

// ---------------------------------------------------------------------------
// In-place att += att^T AND per-tile-row column stats of the result.
__global__ LB void att2_sym_stats(float* __restrict__ att,
                                  float* __restrict__ Mp2, float* __restrict__ Sp2, int N)
{
    const int ti = blockIdx.x, tj = blockIdx.y;
    if (ti > tj) return;
    const int b = blockIdx.z;
    __shared__ float Ta[32][33], Tb[32][33];
    __shared__ float pm[8][33], ps[8][33];
    const long base = (long)b * N * N;
    const int tid = threadIdx.x;
    const int r = tid >> 5, col = tid & 31;
    #pragma unroll
    for (int i = 0; i < 4; ++i) {
        const int rr = r + i * 8;
        Ta[rr][col] = att[base + (long)(ti * 32 + rr) * N + tj * 32 + col];
        Tb[rr][col] = att[base + (long)(tj * 32 + rr) * N + ti * 32 + col];
    }
    __syncthreads();
    float va[4], vb[4];
    #pragma unroll
    for (int i = 0; i < 4; ++i) {
        const int rr = r + i * 8;
        va[i] = Ta[rr][col] + Tb[col][rr];
        att[base + (long)(ti * 32 + rr) * N + tj * 32 + col] = va[i];
        if (ti != tj) {
            vb[i] = Tb[rr][col] + Ta[col][rr];
            att[base + (long)(tj * 32 + rr) * N + ti * 32 + col] = vb[i];
        }
    }
    float mx = NEG_BIG, sm = 0.f;
    #pragma unroll
    for (int i = 0; i < 4; ++i) {
        const float v = va[i];
        const float mn = fmaxf(mx, v);
        sm = sm * __expf(mx - mn) + __expf(v - mn);
        mx = mn;
    }
    pm[r][col] = mx; ps[r][col] = sm;
    __syncthreads();
    if (tid < 32) {
        float mx2 = NEG_BIG, sm2 = 0.f;
        #pragma unroll
        for (int w = 0; w < 8; ++w) {
            const float m2 = pm[w][tid], s2 = ps[w][tid];
            const float mn = fmaxf(mx2, m2);
            sm2 = sm2 * __expf(mx2 - mn) + s2 * __expf(m2 - mn);
            mx2 = mn;
        }
        Mp2[((long)b * 128 + ti) * N + tj * 32 + tid] = mx2;
        Sp2[((long)b * 128 + ti) * N + tj * 32 + tid] = sm2;
    }
    if (ti != tj) {
        __syncthreads();
        float mxb = NEG_BIG, smb = 0.f;
        #pragma unroll
        for (int i = 0; i < 4; ++i) {
            const float v = vb[i];
            const float mn = fmaxf(mxb, v);
            smb = smb * __expf(mxb - mn) + __expf(v - mn);
            mxb = mn;
        }
        pm[r][col] = mxb; ps[r][col] = smb;
        __syncthreads();
        if (tid < 32) {
            float mx2 = NEG_BIG, sm2 = 0.f;
            #pragma unroll
            for (int w = 0; w < 8; ++w) {
                const float m2 = pm[w][tid], s2 = ps[w][tid];
                const float mn = fmaxf(mx2, m2);
                sm2 = sm2 * __expf(mx2 - mn) + s2 * __expf(m2 - mn);
                mx2 = mn;
            }
            Mp2[((long)b * 128 + tj) * N + ti * 32 + tid] = mx2;
            Sp2[((long)b * 128 + tj) * N + ti * 32 + tid] = sm2;
        }
    }
}

// ---------------------------------------------------------------------------
// Fused: att3 = 2*exp(att2 - M2[m])/S2[m], then 3x3 conv + BN + ReLU.
__global__ LB void attmap_conv(const float* __restrict__ att2,
                               const float* __restrict__ M2, const float* __restrict__ S2,
                               const float* __restrict__ w, const float* __restrict__ g,
                               float* __restrict__ out, int N)
{
    __shared__ float t[6][67];
    const int tid = threadIdx.x;
    const int tx = tid & 63, ty = tid >> 6;
    const int x0 = (blockIdx.x & 63) * 64;
    const int y0 = (blockIdx.x >> 6) * 4;
    const int b = blockIdx.y;
    const float* ap = att2 + (long)b * N * N;
    const float* m2p = M2 + (long)b * N;
    const float* s2p = S2 + (long)b * N;
    for (int e = tid; e < 396; e += 256) {
        const int hy = e / 66, hx = e % 66;
        const int yy = y0 + hy - 1, xx = x0 + hx - 1;
        float v = 0.f;
        if ((unsigned)yy < (unsigned)N && (unsigned)xx < (unsigned)N)
            v = 2.f * __expf(ap[(long)yy * N + xx] - m2p[xx]) *
                __builtin_amdgcn_rcpf(s2p[xx]);
        t[hy][hx] = v;
    }
    __syncthreads();
    float acc = 0.f;
    #pragma unroll
    for (int k = 0; k < 9; ++k)
        acc = fmaf(w[k], t[ty + k / 3][tx + k % 3], acc);
    const float scale = g[0] * BN_SCALE, beta = g[1];
    out[(long)b * N * N + (long)(y0 + ty) * N + x0 + tx] =
        fmaxf(fmaf(acc, scale, beta), 0.f);
}

// ===========================================================================
extern "C" void kernel_launch(void* const* d_in, const int* in_sizes, int n_in,
                              void* d_out, int out_size, void* d_ws, size_t ws_size,
                              hipStream_t stream)
{
    const float* xs   = (const float*)d_in[0];
    const float* xc   = (const float*)d_in[1];
    const float* w_g1 = (const float*)d_in[2];
    const float* g_g1 = (const float*)d_in[3];
    const float* w_g2 = (const float*)d_in[4];
    const float* g_g2 = (const float*)d_in[5];
    const float* w_ls = (const float*)d_in[6];
    const float* b_ls = (const float*)d_in[7];
    const float* g_ls = (const float*)d_in[8];
    const float* w_lc = (const float*)d_in[9];
    const float* b_lc = (const float*)d_in[10];
    const float* g_lc = (const float*)d_in[11];
    const float* w_c1 = (const float*)d_in[12];
    const float* g_c1 = (const float*)d_in[13];
    const float* w_c2 = (const float*)d_in[14];
    const float* g_c2 = (const float*)d_in[15];
    const float* w_o1 = (const float*)d_in[16];
    const float* g_o1 = (const float*)d_in[17];
    const float* w_o2 = (const float*)d_in[18];
    const float* g_o2 = (const float*)d_in[19];
    const float* w_oa = (const float*)d_in[20];
    const float* g_oa = (const float*)d_in[21];

    const int B = 2, HW = 4096, N = 4096;

    // ---- workspace layout (float offsets) ----
    float* ws = (float*)d_ws;
    float* xs1    = ws;                       // 524288
    float* xc1    = ws + 524288;              // 1048576
    float* fs     = ws + 1572864;             // 262144
    float* fc     = ws + 1835008;             // 262144
    float* t32    = ws + 2097152;             // 262144
    float* outs_w = ws + 2359296;             // 524288
    float* outc_w = ws + 2883584;             // 1048576
    float* gs_w   = ws + 3932160;             // 64
    float* gc_w   = ws + 3932224;             // 64
    float* Mc     = ws + 3932288;             // 8192
    float* Sc     = ws + 3940480;             // 8192
    float* Mr     = ws + 3948672;             // 8192
    float* Sr     = ws + 3956864;             // 8192
    float* M2     = ws + 3965056;             // 8192
    float* S2     = ws + 3973248;             // 8192
    float* Mp     = ws + 3981440;             // 131072
    float* Sp     = ws + 4112512;             // 131072
    float* att    = ws + 4243584;             // 33554432
    float* cpart  = att;                      // conv partials alias (att dead then)

    // ---- d_out layout ----
    float* out = (float*)d_out;
    float* out_attmap = out;                       // 33554432 (scratch until end)
    float* out_s      = out + 33554432;            // 524288
    float* out_c      = out + 34078720;            // 1048576
    float* out_gs     = out + 35127296;            // 64
    float* out_gc     = out + 35127360;            // 64
    float* Mp2        = out;                       // [B,128,N] (after GEMM partials die)
    float* Sp2        = out + 1048576;

    const dim3 blk(256);
    const int ICS = 8;

    // global context s: conv g1 (64->32) -> BN/ReLU -> GAP
    conv3x3_big<<<dim3(4, 4, B * ICS), blk, 0, stream>>>(xs, nullptr, w_g1, nullptr, cpart, 0, 64, 32, ICS);
    conv_combine<<<dim3((B * 32 * HW) / 256), blk, 0, stream>>>(cpart, g_g1, nullptr, t32, 32, ICS);
    gap_kernel<<<dim3(32, B), blk, 0, stream>>>(t32, gs_w, out_gs, 32, HW);
    // global context c: conv g2 (128->32)
    conv3x3_big<<<dim3(4, 4, B * ICS), blk, 0, stream>>>(xc, nullptr, w_g2, nullptr, cpart, 0, 128, 32, ICS);
    conv_combine<<<dim3((B * 32 * HW) / 256), blk, 0, stream>>>(cpart, g_g2, nullptr, t32, 32, ICS);
    gap_kernel<<<dim3(32, B), blk, 0, stream>>>(t32, gc_w, out_gc, 32, HW);
    // local fusion convs (+bias, +const channels) + residual
    conv3x3_big<<<dim3(4, 8, B * ICS), blk, 0, stream>>>(xs, gs_w, w_ls, b_ls, cpart, 32, 64, 64, ICS);
    conv_combine<<<dim3((B * 64 * HW) / 256), blk, 0, stream>>>(cpart, g_ls, xs, xs1, 64, ICS);
    conv3x3_big<<<dim3(4, 16, B * ICS), blk, 0, stream>>>(xc, gc_w, w_lc, b_lc, cpart, 32, 128, 128, ICS);
    conv_combine<<<dim3((B * 128 * HW) / 256), blk, 0, stream>>>(cpart, g_lc, xc, xc1, 128, ICS);
    // attention features
    conv3x3_big<<<dim3(4, 4, B * ICS), blk, 0, stream>>>(xs1, nullptr, w_c1, nullptr, cpart, 0, 64, 32, ICS);
    conv_combine<<<dim3((B * 32 * HW) / 256), blk, 0, stream>>>(cpart, g_c1, nullptr, fs, 32, ICS);
    conv3x3_big<<<dim3(4, 4, B * ICS), blk, 0, stream>>>(xc1, nullptr, w_c2, nullptr, cpart, 0, 128, 32, ICS);
    conv_combine<<<dim3((B * 32 * HW) / 256), blk, 0, stream>>>(cpart, g_c2, nullptr, fc, 32, ICS);
    // att = fs^T fc  (overwrites cpart region — conv partials dead)
    att_gemm<<<dim3(16, 256, B), blk, 0, stream>>>(fs, fc, att, N);
    // column stats of att
    colstats_part<<<dim3(16, 16, B), blk, 0, stream>>>(att, Mp, Sp, N, 16);
    colstats_comb<<<dim3(16, B), blk, 0, stream>>>(Mp, Sp, Mc, Sc, N, 16);
    // row stats of att
    rowstats<<<dim3(N, B), blk, 0, stream>>>(att, Mr, Sr, N);
    // outs = xs1 @ colsoftmax(att): tiled GEMM, partials in d_out scratch
    sm_gemm<64, 0><<<dim3(32, 8, B), blk, 0, stream>>>(xs1, att, Mc, out_attmap, N, 8);
    sm_reduce<64><<<dim3((B * 64 * N) / 256), blk, 0, stream>>>(out_attmap, Sc, outs_w, N, 8);
    // outc = xc1 @ rowsoftmax(att)^T: tiled GEMM
    sm_gemm<128, 1><<<dim3(32, 8, B), blk, 0, stream>>>(xc1, att, Mr, out_attmap, N, 8);
    sm_reduce<128><<<dim3((B * 128 * N) / 256), blk, 0, stream>>>(out_attmap, Sr, outc_w, N, 8);
    // att2 = att + att^T in place, with fused column partial stats
    att2_sym_stats<<<dim3(N / 32, N / 32, B), blk, 0, stream>>>(att, Mp2, Sp2, N);
    colstats_comb<<<dim3(16, B), blk, 0, stream>>>(Mp2, Sp2, M2, S2, N, 128);
    // fused att3 + 3x3 conv + BN + ReLU  (writes final att_map)
    attmap_conv<<<dim3(64 * 1024, B), blk, 0, stream>>>(att, M2, S2, w_oa, g_oa, out_attmap, N);
    // output convs + residuals (att region free again for partials)
    conv3x3_big<<<dim3(4, 8, B * ICS), blk, 0, stream>>>(outs_w, nullptr, w_o1, nullptr, cpart, 0, 64, 64, ICS);
    conv_combine<<<dim3((B * 64 * HW) / 256), blk, 0, stream>>>(cpart, g_o1, xs1, out_s, 64, ICS);
    conv3x3_big<<<dim3(4, 16, B * ICS), blk, 0, stream>>>(outc_w, nullptr, w_o2, nullptr, cpart, 0, 128, 128, ICS);
    conv_combine<<<dim3((B * 128 * HW) / 256), blk, 0, stream>>>(cpart, g_o2, xc1, out_c, 128, ICS);
}